// Round 11
// baseline (2762.450 us; speedup 1.0000x reference)
//
#include <hip/hip_runtime.h>
#include <cstddef>
#include <cstdint>

#define NEG_SLOPE 0.2f
#define LN_EPS    1e-5f
#define NBUK      256      // buckets for CSR counting sort (needs N/NBUK+2 <= 512)
#define MAXNPB    512      // max nodes per bucket (LDS histogram size)

typedef unsigned short ushort_t;
typedef short bf16x8 __attribute__((ext_vector_type(8)));
typedef float f32x4  __attribute__((ext_vector_type(4)));

__device__ __forceinline__ float lrelu(float s) { return s >= 0.f ? s : NEG_SLOPE * s; }
__device__ __forceinline__ float b2f(ushort_t u) { return __uint_as_float(((uint32_t)u) << 16); }
__device__ __forceinline__ ushort_t f2b(float f) {   // round-to-nearest-even (finite inputs)
  uint32_t u = __float_as_uint(f);
  return (ushort_t)((u + 0x7fffu + ((u >> 16) & 1u)) >> 16);
}
__device__ __forceinline__ uint2 pack4(float4 v) {
  uint2 r;
  r.x = (uint32_t)f2b(v.x) | ((uint32_t)f2b(v.y) << 16);
  r.y = (uint32_t)f2b(v.z) | ((uint32_t)f2b(v.w) << 16);
  return r;
}

// ================= CSR build: single-pass bucketed counting sort =================
__global__ void kb_init(int* __restrict__ gbcur, int cap) {
  gbcur[threadIdx.x] = threadIdx.x * cap;
}

__global__ __launch_bounds__(256) void kb_expand(const int* __restrict__ src,
                                                 const int* __restrict__ dst, int E,
                                                 int* __restrict__ gbcur,
                                                 int2* __restrict__ pairs, uint32_t bmul) {
  __shared__ int hist[NBUK], base[NBUK], lcnt[NBUK];
  const int tid = threadIdx.x;
  const int nchunk = (E + 4095) >> 12;
  for (int c = blockIdx.x; c < nchunk; c += gridDim.x) {
    const int e0 = c << 12;
    hist[tid] = 0; lcnt[tid] = 0;
    __syncthreads();
    int sv[16], dv[16], bv[16];
    #pragma unroll
    for (int u = 0; u < 16; ++u) {
      const int i = e0 + u * 256 + tid;
      if (i < E) {
        sv[u] = src[i]; dv[u] = dst[i];
        bv[u] = (int)__umulhi((uint32_t)dv[u], bmul);
        atomicAdd(&hist[bv[u]], 1);
      } else bv[u] = -1;
    }
    __syncthreads();
    base[tid] = atomicAdd(&gbcur[tid], hist[tid]);
    __syncthreads();
    #pragma unroll
    for (int u = 0; u < 16; ++u) {
      if (bv[u] >= 0) {
        const int pos = atomicAdd(&lcnt[bv[u]], 1);
        pairs[base[bv[u]] + pos] = make_int2(sv[u], dv[u]);
      }
    }
    __syncthreads();
  }
}

__global__ __launch_bounds__(256) void kb_sort(const int2* __restrict__ pairs,
                                               const int* __restrict__ gbcur,
                                               int* __restrict__ rs, int* __restrict__ re,
                                               int* __restrict__ csr,
                                               uint32_t bmul, int cap, int N) {
  __shared__ int hist[MAXNPB];
  __shared__ int ps[256];
  const int b = blockIdx.x, tid = threadIdx.x;
  int n0 = (int)((((uint64_t)b << 32) + bmul - 1) / bmul);
  int n1 = (int)((((uint64_t)(b + 1) << 32) + bmul - 1) / bmul);
  n0 = n0 < N ? n0 : N;
  n1 = n1 < N ? n1 : N;
  const int nn = n1 - n0;
  const int e0 = b * cap;
  const int e1 = min(gbcur[b], e0 + cap);
  for (int k = tid; k < nn; k += 256) hist[k] = 0;
  __syncthreads();
  for (int i = e0 + tid; i < e1; i += 256) atomicAdd(&hist[pairs[i].y - n0], 1);
  __syncthreads();
  const int i0 = 2 * tid, i1 = 2 * tid + 1;
  const int a = (i0 < nn) ? hist[i0] : 0;
  const int c = (i1 < nn) ? hist[i1] : 0;
  const int tot = a + c;
  ps[tid] = tot;
  __syncthreads();
  for (int off = 1; off < 256; off <<= 1) {
    const int x = (tid >= off) ? ps[tid - off] : 0;
    __syncthreads();
    ps[tid] += x;
    __syncthreads();
  }
  const int excl = ps[tid] - tot;
  if (i0 < nn) { hist[i0] = excl;     rs[n0 + i0] = e0 + excl;     re[n0 + i0] = e0 + excl + a; }
  if (i1 < nn) { hist[i1] = excl + a; rs[n0 + i1] = e0 + excl + a; re[n0 + i1] = e0 + excl + a + c; }
  __syncthreads();
  for (int i = e0 + tid; i < e1; i += 256) {
    const int2 e = pairs[i];
    const int p = atomicAdd(&hist[e.y - n0], 1);
    csr[e0 + p] = e.x;
  }
}

// ---------------- MFMA GEMM (h = act @ W) + attention dots --------------------
// act is f32 for layer 1 (LNF=false), bf16 for layer 2 (LNF=true, y from agg).
// LNF consumers derive (mu, rstd) from raw (sum, sumsq) accumulated by k_aggregate.
template <int FI, bool LNF>
__global__ __launch_bounds__(256) void k_gemm_att(
    const void* __restrict__ act, int N,
    const float* __restrict__ W, const float* __restrict__ a_s, const float* __restrict__ a_d,
    const float* __restrict__ stats, float invCount, const float* __restrict__ g,
    const float* __restrict__ be, const float* __restrict__ pp,
    ushort_t* __restrict__ h16, float* __restrict__ hs, float* __restrict__ hd)
{
  constexpr int P = FI + 8;                 // bf16 row pitch: +16B pad -> 4-bank rotation
  __shared__ ushort_t S[64 * P];            // Wt stage, then act tile / out tile
  const int tid = threadIdx.x, wid = tid >> 6, lane = tid & 63;
  const int l15 = lane & 15, lhi = lane >> 4;

  for (int idx = tid; idx < FI * 64; idx += 256) {
    const int k = idx >> 6, f = idx & 63;
    S[f * P + k] = f2b(W[idx]);
  }
  __syncthreads();
  bf16x8 Bf[FI / 32][4];
  #pragma unroll
  for (int kt = 0; kt < FI / 32; ++kt)
    #pragma unroll
    for (int nt = 0; nt < 4; ++nt)
      Bf[kt][nt] = *(const bf16x8*)&S[(nt * 16 + l15) * P + kt * 32 + lhi * 8];
  __syncthreads();

  float asf[4], adf[4];
  #pragma unroll
  for (int nt = 0; nt < 4; ++nt) { asf[nt] = a_s[nt * 16 + l15]; adf[nt] = a_d[nt * 16 + l15]; }
  float mu = 0.f, rstd = 1.f, p0 = 0.f;
  if (LNF) {
    const float s1 = stats[0], s2 = stats[1];
    mu = s1 * invCount;
    rstd = rsqrtf(s2 * invCount - mu * mu + LN_EPS);
    p0 = pp[0];
  }

  const int ntiles = (N + 63) >> 6;
  for (int tile = blockIdx.x; tile < ntiles; tile += gridDim.x) {
    const int nb = tile << 6;
    {   // stage activation tile -> bf16 LDS
      const int r = tid >> 2;
      const int node = nb + r;
      if (node < N) {
        if (LNF) {   // bf16 input (aggregated y), fuse LN+PReLU
          const ushort_t* a16 = (const ushort_t*)act;
          const int q = tid & 3;   // 16-feature chunk
          const int4* srcp = (const int4*)(a16 + (size_t)node * 64 + q * 16);
          const int4 A0 = srcp[0], A1 = srcp[1];
          const ushort_t* pu0 = (const ushort_t*)&A0;
          const ushort_t* pu1 = (const ushort_t*)&A1;
          float vv[16];
          #pragma unroll
          for (int i = 0; i < 8; ++i) { vv[i] = b2f(pu0[i]); vv[8 + i] = b2f(pu1[i]); }
          #pragma unroll
          for (int i2 = 0; i2 < 4; ++i2) {
            const int c4 = q * 4 + i2;
            const float4 gg = ((const float4*)g)[c4];
            const float4 bb = ((const float4*)be)[c4];
            float4 v;
            v.x = (vv[i2 * 4 + 0] - mu) * rstd * gg.x + bb.x;  v.x = v.x >= 0.f ? v.x : p0 * v.x;
            v.y = (vv[i2 * 4 + 1] - mu) * rstd * gg.y + bb.y;  v.y = v.y >= 0.f ? v.y : p0 * v.y;
            v.z = (vv[i2 * 4 + 2] - mu) * rstd * gg.z + bb.z;  v.z = v.z >= 0.f ? v.z : p0 * v.z;
            v.w = (vv[i2 * 4 + 3] - mu) * rstd * gg.w + bb.w;  v.w = v.w >= 0.f ? v.w : p0 * v.w;
            *(uint2*)&S[r * P + c4 * 4] = pack4(v);
          }
        } else {     // f32 input (x)
          const float4* srcp = (const float4*)((const float*)act + (size_t)node * FI);
          #pragma unroll
          for (int i = 0; i < FI / 16; ++i) {
            const int c = (tid & 3) * (FI / 4) + i * 4;
            const float4 v = srcp[c >> 2];
            *(uint2*)&S[r * P + c] = pack4(v);
          }
        }
      }
    }
    __syncthreads();

    const f32x4 fz = {0.f, 0.f, 0.f, 0.f};
    f32x4 acc[4]; acc[0] = fz; acc[1] = fz; acc[2] = fz; acc[3] = fz;
    #pragma unroll
    for (int kt = 0; kt < FI / 32; ++kt) {
      const bf16x8 Af = *(const bf16x8*)&S[(wid * 16 + l15) * P + kt * 32 + lhi * 8];
      #pragma unroll
      for (int nt = 0; nt < 4; ++nt)
        acc[nt] = __builtin_amdgcn_mfma_f32_16x16x32_bf16(Af, Bf[kt][nt], acc[nt], 0, 0, 0);
    }
    #pragma unroll
    for (int r = 0; r < 4; ++r) {
      float ps = acc[0][r] * asf[0] + acc[1][r] * asf[1] + acc[2][r] * asf[2] + acc[3][r] * asf[3];
      float pd = acc[0][r] * adf[0] + acc[1][r] * adf[1] + acc[2][r] * adf[2] + acc[3][r] * adf[3];
      #pragma unroll
      for (int off = 1; off < 16; off <<= 1) { ps += __shfl_xor(ps, off); pd += __shfl_xor(pd, off); }
      const int node = nb + wid * 16 + lhi * 4 + r;
      if (l15 == 0 && node < N) { hs[node] = ps; hd[node] = pd; }
    }
    #pragma unroll
    for (int nt = 0; nt < 4; ++nt)
      #pragma unroll
      for (int r = 0; r < 4; ++r)
        S[(wid * 16 + lhi * 4 + r) * P + nt * 16 + l15] = f2b(acc[nt][r]);
    __syncthreads();
    {
      const int r = tid >> 2, chunk = tid & 3;
      const int node = nb + r;
      if (node < N) {
        const int4* sp = (const int4*)&S[r * P + chunk * 16];
        const int4 v0 = sp[0], v1 = sp[1];
        int4* dp = (int4*)(h16 + (size_t)node * 64 + chunk * 16);
        dp[0] = v0; dp[1] = v1;
      }
    }
    __syncthreads();
  }
}

// ---------------- GAT aggregation: y_i = (sum_j w_j h_j + w_self h_i)/z + bias ----
// Chunk = 32 edges, static issue/consume split (measured floor ~62us across 3
// structural variants; FETCH ~= 8 XCD x |h16| = structural minimum for random
// graphs). y written as bf16. Graph-LN (sum, sumsq) accumulated via 2 atomics
// per block into statsOut (consumers derive mu/rstd inline).
__global__ __launch_bounds__(256) void k_aggregate(
    const int* __restrict__ rs, const int* __restrict__ re, const int* __restrict__ csr,
    const ushort_t* __restrict__ h16, const float* __restrict__ hs, const float* __restrict__ hd,
    const float* __restrict__ bias, int N,
    ushort_t* __restrict__ y16, float* __restrict__ statsOut)
{
  __shared__ float wsh[4][32];
  __shared__ float sh1[4], sh2[4];
  const int tid = threadIdx.x, wid = tid >> 6, lane = tid & 63;
  const int node = blockIdx.x * 4 + wid;
  float val = 0.f;
  if (node < N) {
    const float hdi = hd[node];
    const float wself = __expf(lrelu(hs[node] + hdi));   // self loop
    float z = wself;
    float acc0 = wself * b2f(h16[((size_t)(uint32_t)node << 6) + lane]);
    float acc1 = 0.f, acc2 = 0.f, acc3 = 0.f;
    const int st = __builtin_amdgcn_readfirstlane(rs[node]);
    const int en = __builtin_amdgcn_readfirstlane(re[node]);
    for (int j = st; j < en; j += 32) {
      const int m = min(32, en - j);
      int sA = 0;
      if (lane < m) sA = csr[j + lane];
      // ---- issue gathers (4-granular) ----
      #define GA(u) h16[((size_t)(uint32_t)__builtin_amdgcn_readlane(sA, u) << 6) + lane]
      ushort_t g0 = 0, g1 = 0, g2 = 0, g3 = 0, g4 = 0, g5 = 0, g6 = 0, g7 = 0;
      ushort_t g8 = 0, g9 = 0, g10 = 0, g11 = 0, g12 = 0, g13 = 0, g14 = 0, g15 = 0;
      ushort_t g16 = 0, g17 = 0, g18 = 0, g19 = 0, g20 = 0, g21 = 0, g22 = 0, g23 = 0;
      ushort_t g24 = 0, g25 = 0, g26 = 0, g27 = 0, g28 = 0, g29 = 0, g30 = 0, g31 = 0;
      if (m > 0)  { g0  = GA(0);  g1  = GA(1);  g2  = GA(2);  g3  = GA(3);  }
      if (m > 4)  { g4  = GA(4);  g5  = GA(5);  g6  = GA(6);  g7  = GA(7);  }
      if (m > 8)  { g8  = GA(8);  g9  = GA(9);  g10 = GA(10); g11 = GA(11); }
      if (m > 12) { g12 = GA(12); g13 = GA(13); g14 = GA(14); g15 = GA(15); }
      if (m > 16) { g16 = GA(16); g17 = GA(17); g18 = GA(18); g19 = GA(19); }
      if (m > 20) { g20 = GA(20); g21 = GA(21); g22 = GA(22); g23 = GA(23); }
      if (m > 24) { g24 = GA(24); g25 = GA(25); g26 = GA(26); g27 = GA(27); }
      if (m > 28) { g28 = GA(28); g29 = GA(29); g30 = GA(30); g31 = GA(31); }
      #undef GA
      // ---- weights (overlap with gather latency) ----
      float wA = 0.f;
      if (lane < m) wA = __expf(lrelu(hs[sA] + hdi));
      if (lane < 32) wsh[wid][lane] = wA;    // full 32 slots (0-padded)
      float ws = wA;
      #pragma unroll
      for (int off = 32; off; off >>= 1) ws += __shfl_xor(ws, off);
      z += ws;
      // ---- consume ----
      #define CS(u, a) a = fmaf(wsh[wid][u], b2f(g##u), a)
      if (m > 0)  { CS(0, acc0);  CS(1, acc1);  CS(2, acc2);  CS(3, acc3);  }
      if (m > 4)  { CS(4, acc0);  CS(5, acc1);  CS(6, acc2);  CS(7, acc3);  }
      if (m > 8)  { CS(8, acc0);  CS(9, acc1);  CS(10, acc2); CS(11, acc3); }
      if (m > 12) { CS(12, acc0); CS(13, acc1); CS(14, acc2); CS(15, acc3); }
      if (m > 16) { CS(16, acc0); CS(17, acc1); CS(18, acc2); CS(19, acc3); }
      if (m > 20) { CS(20, acc0); CS(21, acc1); CS(22, acc2); CS(23, acc3); }
      if (m > 24) { CS(24, acc0); CS(25, acc1); CS(26, acc2); CS(27, acc3); }
      if (m > 28) { CS(28, acc0); CS(29, acc1); CS(30, acc2); CS(31, acc3); }
      #undef CS
    }
    val = ((acc0 + acc1) + (acc2 + acc3)) / z + bias[lane];
    y16[(size_t)node * 64 + lane] = f2b(val);
  }
  float s1r = val, s2r = val * val;
  #pragma unroll
  for (int off = 32; off; off >>= 1) { s1r += __shfl_xor(s1r, off); s2r += __shfl_xor(s2r, off); }
  if (lane == 0) { sh1[wid] = s1r; sh2[wid] = s2r; }
  __syncthreads();
  if (tid == 0) {
    atomicAdd(&statsOut[0], sh1[0] + sh1[1] + sh1[2] + sh1[3]);
    atomicAdd(&statsOut[1], sh2[0] + sh2[1] + sh2[2] + sh2[3]);
  }
}

// ---------------- MLP head (MFMA): out = prelu(LN(y) @ W1 + b1) @ W2 + b2 -------
__global__ __launch_bounds__(256) void k_mlp(
    const ushort_t* __restrict__ y16, int N,
    const float* __restrict__ stats, float invCount, const float* __restrict__ g,
    const float* __restrict__ be, const float* __restrict__ pe,
    const float* __restrict__ W1, const float* __restrict__ b1, const float* __restrict__ pm,
    const float* __restrict__ W2, const float* __restrict__ b2,
    float* __restrict__ outp)
{
  __shared__ ushort_t W1t[128 * 72];   // W1^T bf16 [f=128][k=64],  pitch 72
  __shared__ ushort_t W2t[64 * 136];   // W2^T bf16 [f=64][k=128],  pitch 136
  __shared__ ushort_t At[64 * 72];     // LN(y) tile bf16
  __shared__ ushort_t Tt[64 * 136];    // hidden tile bf16
  __shared__ float    Ob[64 * 68];     // out tile f32
  const int tid = threadIdx.x, wid = tid >> 6, lane = tid & 63;
  const int l15 = lane & 15, lhi = lane >> 4;

  for (int idx = tid; idx < 64 * 128; idx += 256) {   // W1 [64][128]
    const int k = idx >> 7, f = idx & 127;
    W1t[f * 72 + k] = f2b(W1[idx]);
  }
  for (int idx = tid; idx < 128 * 64; idx += 256) {   // W2 [128][64]
    const int k = idx >> 6, f = idx & 63;
    W2t[f * 136 + k] = f2b(W2[idx]);
  }
  __syncthreads();

  const float s1 = stats[0], s2 = stats[1];
  const float mu = s1 * invCount;
  const float rstd = rsqrtf(s2 * invCount - mu * mu + LN_EPS);
  const float p0 = pe[0], pm0 = pm[0];
  float b1f[8], b2f_[4];
  #pragma unroll
  for (int nt = 0; nt < 8; ++nt) b1f[nt] = b1[nt * 16 + l15];
  #pragma unroll
  for (int nt = 0; nt < 4; ++nt) b2f_[nt] = b2[nt * 16 + l15];

  const int ntiles = (N + 63) >> 6;
  for (int tile = blockIdx.x; tile < ntiles; tile += gridDim.x) {
    const int nb = tile << 6;
    {   // stage LN(y)+prelu tile from bf16 y
      const int r = tid >> 2;
      const int node = nb + r;
      if (node < N) {
        const int q = tid & 3;
        const int4* srcp = (const int4*)(y16 + (size_t)node * 64 + q * 16);
        const int4 A0 = srcp[0], A1 = srcp[1];
        const ushort_t* pu0 = (const ushort_t*)&A0;
        const ushort_t* pu1 = (const ushort_t*)&A1;
        float vv[16];
        #pragma unroll
        for (int i = 0; i < 8; ++i) { vv[i] = b2f(pu0[i]); vv[8 + i] = b2f(pu1[i]); }
        #pragma unroll
        for (int i2 = 0; i2 < 4; ++i2) {
          const int c4 = q * 4 + i2;
          const float4 gg = ((const float4*)g)[c4];
          const float4 bb = ((const float4*)be)[c4];
          float4 v;
          v.x = (vv[i2 * 4 + 0] - mu) * rstd * gg.x + bb.x;  v.x = v.x >= 0.f ? v.x : p0 * v.x;
          v.y = (vv[i2 * 4 + 1] - mu) * rstd * gg.y + bb.y;  v.y = v.y >= 0.f ? v.y : p0 * v.y;
          v.z = (vv[i2 * 4 + 2] - mu) * rstd * gg.z + bb.z;  v.z = v.z >= 0.f ? v.z : p0 * v.z;
          v.w = (vv[i2 * 4 + 3] - mu) * rstd * gg.w + bb.w;  v.w = v.w >= 0.f ? v.w : p0 * v.w;
          *(uint2*)&At[r * 72 + c4 * 4] = pack4(v);
        }
      }
    }
    __syncthreads();

    const f32x4 fz = {0.f, 0.f, 0.f, 0.f};
    f32x4 acc1[8];
    #pragma unroll
    for (int nt = 0; nt < 8; ++nt) acc1[nt] = fz;
    #pragma unroll
    for (int kt = 0; kt < 2; ++kt) {
      const bf16x8 Af = *(const bf16x8*)&At[(wid * 16 + l15) * 72 + kt * 32 + lhi * 8];
      #pragma unroll
      for (int nt = 0; nt < 8; ++nt) {
        const bf16x8 Bf = *(const bf16x8*)&W1t[(nt * 16 + l15) * 72 + kt * 32 + lhi * 8];
        acc1[nt] = __builtin_amdgcn_mfma_f32_16x16x32_bf16(Af, Bf, acc1[nt], 0, 0, 0);
      }
    }
    #pragma unroll
    for (int nt = 0; nt < 8; ++nt)
      #pragma unroll
      for (int r = 0; r < 4; ++r) {
        float v = acc1[nt][r] + b1f[nt];
        v = v >= 0.f ? v : pm0 * v;
        Tt[(wid * 16 + lhi * 4 + r) * 136 + nt * 16 + l15] = f2b(v);
      }
    __syncthreads();

    f32x4 acc2[4];
    #pragma unroll
    for (int nt = 0; nt < 4; ++nt) acc2[nt] = fz;
    #pragma unroll
    for (int kt = 0; kt < 4; ++kt) {
      const bf16x8 Af = *(const bf16x8*)&Tt[(wid * 16 + l15) * 136 + kt * 32 + lhi * 8];
      #pragma unroll
      for (int nt = 0; nt < 4; ++nt) {
        const bf16x8 Bf = *(const bf16x8*)&W2t[(nt * 16 + l15) * 136 + kt * 32 + lhi * 8];
        acc2[nt] = __builtin_amdgcn_mfma_f32_16x16x32_bf16(Af, Bf, acc2[nt], 0, 0, 0);
      }
    }
    #pragma unroll
    for (int nt = 0; nt < 4; ++nt)
      #pragma unroll
      for (int r = 0; r < 4; ++r)
        Ob[(wid * 16 + lhi * 4 + r) * 68 + nt * 16 + l15] = acc2[nt][r] + b2f_[nt];
    __syncthreads();
    {
      const int r = tid >> 2, chunk = tid & 3;
      const int node = nb + r;
      if (node < N) {
        const float4* sp = (const float4*)&Ob[r * 68 + chunk * 16];
        const float4 v0 = sp[0], v1 = sp[1], v2 = sp[2], v3 = sp[3];
        float4* dp = (float4*)(outp + (size_t)node * 64 + chunk * 16);
        dp[0] = v0; dp[1] = v1; dp[2] = v2; dp[3] = v3;
      }
    }
    __syncthreads();
  }
}

// ---------------- K-encoder final LN+PReLU (bf16 y -> f32 out) ------------------
__global__ void k_ln_prelu_out(const ushort_t* __restrict__ y16, int total8,
                               const float* __restrict__ stats, float invCount,
                               const float* __restrict__ g,
                               const float* __restrict__ be, const float* __restrict__ pe,
                               float* __restrict__ o)
{
  const float s1 = stats[0], s2 = stats[1];
  const float mu = s1 * invCount;
  const float rstd = rsqrtf(s2 * invCount - mu * mu + LN_EPS);
  const float p0 = pe[0];
  int i = blockIdx.x * blockDim.x + threadIdx.x;
  const int stride = gridDim.x * blockDim.x;
  for (; i < total8; i += stride) {
    const int4 A = *(const int4*)(y16 + (size_t)i * 8);
    const ushort_t* pu = (const ushort_t*)&A;
    const int grp = i & 7;
    const float4 g0 = ((const float4*)g)[grp * 2], g1 = ((const float4*)g)[grp * 2 + 1];
    const float4 b0 = ((const float4*)be)[grp * 2], b1 = ((const float4*)be)[grp * 2 + 1];
    float4 o0, o1;
    o0.x = (b2f(pu[0]) - mu) * rstd * g0.x + b0.x;  o0.x = o0.x >= 0.f ? o0.x : p0 * o0.x;
    o0.y = (b2f(pu[1]) - mu) * rstd * g0.y + b0.y;  o0.y = o0.y >= 0.f ? o0.y : p0 * o0.y;
    o0.z = (b2f(pu[2]) - mu) * rstd * g0.z + b0.z;  o0.z = o0.z >= 0.f ? o0.z : p0 * o0.z;
    o0.w = (b2f(pu[3]) - mu) * rstd * g0.w + b0.w;  o0.w = o0.w >= 0.f ? o0.w : p0 * o0.w;
    o1.x = (b2f(pu[4]) - mu) * rstd * g1.x + b1.x;  o1.x = o1.x >= 0.f ? o1.x : p0 * o1.x;
    o1.y = (b2f(pu[5]) - mu) * rstd * g1.y + b1.y;  o1.y = o1.y >= 0.f ? o1.y : p0 * o1.y;
    o1.z = (b2f(pu[6]) - mu) * rstd * g1.z + b1.z;  o1.z = o1.z >= 0.f ? o1.z : p0 * o1.z;
    o1.w = (b2f(pu[7]) - mu) * rstd * g1.w + b1.w;  o1.w = o1.w >= 0.f ? o1.w : p0 * o1.w;
    float4* dp = (float4*)(o + (size_t)i * 8);
    dp[0] = o0; dp[1] = o1;
  }
}

// ================================================================================
extern "C" void kernel_launch(void* const* d_in, const int* in_sizes, int n_in,
                              void* d_out, int out_size, void* d_ws, size_t ws_size,
                              hipStream_t stream) {
  (void)n_in; (void)out_size; (void)ws_size;
  const int FIN = 128, F = 64;
  const int N = in_sizes[0] / FIN;
  const int E = in_sizes[2] / 2;

  const float* x_q = (const float*)d_in[0];
  const float* x_k = (const float*)d_in[1];
  const int*   ei_q = (const int*)d_in[2];
  const int*   ei_k = (const int*)d_in[3];
  const float* L[4][7];
  for (int l = 0; l < 4; ++l)
    for (int j = 0; j < 7; ++j) L[l][j] = (const float*)d_in[4 + l * 7 + j];
  const float* mW1 = (const float*)d_in[32];
  const float* mb1 = (const float*)d_in[33];
  const float* mp  = (const float*)d_in[34];
  const float* mW2 = (const float*)d_in[35];
  const float* mb2 = (const float*)d_in[36];
  float* out = (float*)d_out;

  const int CAP = (((E + NBUK - 1) / NBUK) * 3 / 2 + 3) & ~3;   // 1.5x mean bucket fill

  char* w = (char*)d_ws;
  auto alloc = [&](size_t bytes) { char* r = w; w += (bytes + 255) & ~size_t(255); return r; };
  ushort_t* h16 = (ushort_t*)alloc((size_t)N * F * sizeof(ushort_t));
  ushort_t* y16 = (ushort_t*)alloc((size_t)N * F * sizeof(ushort_t));
  float* hs    = (float*)alloc((size_t)N * sizeof(float));
  float* hd    = (float*)alloc((size_t)N * sizeof(float));
  float* stats = (float*)alloc(16 * sizeof(float));   // 4 layers x (sum, sumsq)
  int* rs      = (int*)alloc((size_t)N * sizeof(int));
  int* re      = (int*)alloc((size_t)N * sizeof(int));
  int* csr     = (int*)alloc((size_t)NBUK * CAP * sizeof(int));
  int* bcur    = (int*)alloc(NBUK * sizeof(int));
  int2* pairs  = (int2*)alloc((size_t)NBUK * CAP * sizeof(int2));

  const float invCount = 1.f / ((float)N * (float)F);
  const uint32_t bmul = (uint32_t)(((uint64_t)NBUK << 32) / (uint64_t)N);
  const int nblk = (N + 3) / 4;
  const int ntiles = (N + 63) / 64;
  const int nchunkE = (E + 4095) >> 12;

  hipMemsetAsync(stats, 0, 8 * sizeof(float), stream);   // 4 x (sum, sumsq)

  auto build_csr = [&](const int* ei) {
    kb_init<<<1, NBUK, 0, stream>>>(bcur, CAP);
    kb_expand<<<nchunkE, 256, 0, stream>>>(ei, ei + E, E, bcur, pairs, bmul);
    kb_sort<<<NBUK, 256, 0, stream>>>(pairs, bcur, rs, re, csr, bmul, CAP, N);
  };

  auto run_layers = [&](const float* x0, int li0) {
    const float* const* A = L[li0];
    k_gemm_att<128, false><<<ntiles, 256, 0, stream>>>(
        x0, N, A[0], A[1], A[2], nullptr, 0.f, nullptr, nullptr, nullptr, h16, hs, hd);
    k_aggregate<<<nblk, 256, 0, stream>>>(rs, re, csr, h16, hs, hd, A[3], N, y16,
                                          stats + 2 * li0);
    const float* const* B = L[li0 + 1];
    k_gemm_att<64, true><<<ntiles, 256, 0, stream>>>(
        y16, N, B[0], B[1], B[2], stats + 2 * li0, invCount, A[4], A[5], A[6], h16, hs, hd);
    k_aggregate<<<nblk, 256, 0, stream>>>(rs, re, csr, h16, hs, hd, B[3], N, y16,
                                          stats + 2 * (li0 + 1));
  };

  // ---- Q path ----
  build_csr(ei_q);
  run_layers(x_q, 0);
  k_mlp<<<512, 256, 0, stream>>>(y16, N, stats + 2, invCount, L[1][4], L[1][5], L[1][6],
                                 mW1, mb1, mp, mW2, mb2, out);

  // ---- K path (reuses all scratch) ----
  build_csr(ei_k);
  run_layers(x_k, 2);
  const int total8 = N * F / 8;
  k_ln_prelu_out<<<2048, 256, 0, stream>>>(y16, total8, stats + 6, invCount,
                                           L[3][4], L[3][5], L[3][6],
                                           out + (size_t)N * F);
}

// Round 12
// 467.450 us; speedup vs baseline: 5.9096x; 5.9096x over previous
//
#include <hip/hip_runtime.h>
#include <cstddef>
#include <cstdint>

#define NEG_SLOPE 0.2f
#define LN_EPS    1e-5f
#define NBUK      256      // buckets for CSR counting sort (needs N/NBUK+2 <= 512)
#define MAXNPB    512      // max nodes per bucket (LDS histogram size)
#define NSLOT     128      // stats accumulation slots (1 cache line each)
#define SLOTF     32       // floats per slot (128 B)

typedef unsigned short ushort_t;
typedef short bf16x8 __attribute__((ext_vector_type(8)));
typedef float f32x4  __attribute__((ext_vector_type(4)));

__device__ __forceinline__ float lrelu(float s) { return s >= 0.f ? s : NEG_SLOPE * s; }
__device__ __forceinline__ float b2f(ushort_t u) { return __uint_as_float(((uint32_t)u) << 16); }
__device__ __forceinline__ ushort_t f2b(float f) {   // round-to-nearest-even (finite inputs)
  uint32_t u = __float_as_uint(f);
  return (ushort_t)((u + 0x7fffu + ((u >> 16) & 1u)) >> 16);
}
__device__ __forceinline__ uint2 pack4(float4 v) {
  uint2 r;
  r.x = (uint32_t)f2b(v.x) | ((uint32_t)f2b(v.y) << 16);
  r.y = (uint32_t)f2b(v.z) | ((uint32_t)f2b(v.w) << 16);
  return r;
}
// reduce the 128 slot-pairs -> (mu, rstd). Uniform broadcast loads, ~256 L2 hits.
__device__ __forceinline__ void ln_from_slots(const float* __restrict__ stats,
                                              float invCount, float& mu, float& rstd) {
  float s1 = 0.f, s2 = 0.f;
  #pragma unroll 8
  for (int s = 0; s < NSLOT; ++s) { s1 += stats[s * SLOTF]; s2 += stats[s * SLOTF + 1]; }
  mu = s1 * invCount;
  rstd = rsqrtf(s2 * invCount - mu * mu + LN_EPS);
}

// ================= CSR build: single-pass bucketed counting sort =================
__global__ void kb_init(int* __restrict__ gbcur, int cap) {
  gbcur[threadIdx.x] = threadIdx.x * cap;
}

__global__ __launch_bounds__(256) void kb_expand(const int* __restrict__ src,
                                                 const int* __restrict__ dst, int E,
                                                 int* __restrict__ gbcur,
                                                 int2* __restrict__ pairs, uint32_t bmul) {
  __shared__ int hist[NBUK], base[NBUK], lcnt[NBUK];
  const int tid = threadIdx.x;
  const int nchunk = (E + 4095) >> 12;
  for (int c = blockIdx.x; c < nchunk; c += gridDim.x) {
    const int e0 = c << 12;
    hist[tid] = 0; lcnt[tid] = 0;
    __syncthreads();
    int sv[16], dv[16], bv[16];
    #pragma unroll
    for (int u = 0; u < 16; ++u) {
      const int i = e0 + u * 256 + tid;
      if (i < E) {
        sv[u] = src[i]; dv[u] = dst[i];
        bv[u] = (int)__umulhi((uint32_t)dv[u], bmul);
        atomicAdd(&hist[bv[u]], 1);
      } else bv[u] = -1;
    }
    __syncthreads();
    base[tid] = atomicAdd(&gbcur[tid], hist[tid]);
    __syncthreads();
    #pragma unroll
    for (int u = 0; u < 16; ++u) {
      if (bv[u] >= 0) {
        const int pos = atomicAdd(&lcnt[bv[u]], 1);
        pairs[base[bv[u]] + pos] = make_int2(sv[u], dv[u]);
      }
    }
    __syncthreads();
  }
}

__global__ __launch_bounds__(256) void kb_sort(const int2* __restrict__ pairs,
                                               const int* __restrict__ gbcur,
                                               int* __restrict__ rs, int* __restrict__ re,
                                               int* __restrict__ csr,
                                               uint32_t bmul, int cap, int N) {
  __shared__ int hist[MAXNPB];
  __shared__ int ps[256];
  const int b = blockIdx.x, tid = threadIdx.x;
  int n0 = (int)((((uint64_t)b << 32) + bmul - 1) / bmul);
  int n1 = (int)((((uint64_t)(b + 1) << 32) + bmul - 1) / bmul);
  n0 = n0 < N ? n0 : N;
  n1 = n1 < N ? n1 : N;
  const int nn = n1 - n0;
  const int e0 = b * cap;
  const int e1 = min(gbcur[b], e0 + cap);
  for (int k = tid; k < nn; k += 256) hist[k] = 0;
  __syncthreads();
  for (int i = e0 + tid; i < e1; i += 256) atomicAdd(&hist[pairs[i].y - n0], 1);
  __syncthreads();
  const int i0 = 2 * tid, i1 = 2 * tid + 1;
  const int a = (i0 < nn) ? hist[i0] : 0;
  const int c = (i1 < nn) ? hist[i1] : 0;
  const int tot = a + c;
  ps[tid] = tot;
  __syncthreads();
  for (int off = 1; off < 256; off <<= 1) {
    const int x = (tid >= off) ? ps[tid - off] : 0;
    __syncthreads();
    ps[tid] += x;
    __syncthreads();
  }
  const int excl = ps[tid] - tot;
  if (i0 < nn) { hist[i0] = excl;     rs[n0 + i0] = e0 + excl;     re[n0 + i0] = e0 + excl + a; }
  if (i1 < nn) { hist[i1] = excl + a; rs[n0 + i1] = e0 + excl + a; re[n0 + i1] = e0 + excl + a + c; }
  __syncthreads();
  for (int i = e0 + tid; i < e1; i += 256) {
    const int2 e = pairs[i];
    const int p = atomicAdd(&hist[e.y - n0], 1);
    csr[e0 + p] = e.x;
  }
}

// ---------------- MFMA GEMM (h = act @ W) + attention dots --------------------
// act is f32 for layer 1 (LNF=false), bf16 for layer 2 (LNF=true, y from agg).
// LNF consumers derive (mu, rstd) from the 128 slot-pair raw sums.
template <int FI, bool LNF>
__global__ __launch_bounds__(256) void k_gemm_att(
    const void* __restrict__ act, int N,
    const float* __restrict__ W, const float* __restrict__ a_s, const float* __restrict__ a_d,
    const float* __restrict__ stats, float invCount, const float* __restrict__ g,
    const float* __restrict__ be, const float* __restrict__ pp,
    ushort_t* __restrict__ h16, float* __restrict__ hs, float* __restrict__ hd)
{
  constexpr int P = FI + 8;                 // bf16 row pitch: +16B pad -> 4-bank rotation
  __shared__ ushort_t S[64 * P];            // Wt stage, then act tile / out tile
  const int tid = threadIdx.x, wid = tid >> 6, lane = tid & 63;
  const int l15 = lane & 15, lhi = lane >> 4;

  for (int idx = tid; idx < FI * 64; idx += 256) {
    const int k = idx >> 6, f = idx & 63;
    S[f * P + k] = f2b(W[idx]);
  }
  __syncthreads();
  bf16x8 Bf[FI / 32][4];
  #pragma unroll
  for (int kt = 0; kt < FI / 32; ++kt)
    #pragma unroll
    for (int nt = 0; nt < 4; ++nt)
      Bf[kt][nt] = *(const bf16x8*)&S[(nt * 16 + l15) * P + kt * 32 + lhi * 8];
  __syncthreads();

  float asf[4], adf[4];
  #pragma unroll
  for (int nt = 0; nt < 4; ++nt) { asf[nt] = a_s[nt * 16 + l15]; adf[nt] = a_d[nt * 16 + l15]; }
  float mu = 0.f, rstd = 1.f, p0 = 0.f;
  if (LNF) {
    ln_from_slots(stats, invCount, mu, rstd);
    p0 = pp[0];
  }

  const int ntiles = (N + 63) >> 6;
  for (int tile = blockIdx.x; tile < ntiles; tile += gridDim.x) {
    const int nb = tile << 6;
    {   // stage activation tile -> bf16 LDS
      const int r = tid >> 2;
      const int node = nb + r;
      if (node < N) {
        if (LNF) {   // bf16 input (aggregated y), fuse LN+PReLU
          const ushort_t* a16 = (const ushort_t*)act;
          const int q = tid & 3;   // 16-feature chunk
          const int4* srcp = (const int4*)(a16 + (size_t)node * 64 + q * 16);
          const int4 A0 = srcp[0], A1 = srcp[1];
          const ushort_t* pu0 = (const ushort_t*)&A0;
          const ushort_t* pu1 = (const ushort_t*)&A1;
          float vv[16];
          #pragma unroll
          for (int i = 0; i < 8; ++i) { vv[i] = b2f(pu0[i]); vv[8 + i] = b2f(pu1[i]); }
          #pragma unroll
          for (int i2 = 0; i2 < 4; ++i2) {
            const int c4 = q * 4 + i2;
            const float4 gg = ((const float4*)g)[c4];
            const float4 bb = ((const float4*)be)[c4];
            float4 v;
            v.x = (vv[i2 * 4 + 0] - mu) * rstd * gg.x + bb.x;  v.x = v.x >= 0.f ? v.x : p0 * v.x;
            v.y = (vv[i2 * 4 + 1] - mu) * rstd * gg.y + bb.y;  v.y = v.y >= 0.f ? v.y : p0 * v.y;
            v.z = (vv[i2 * 4 + 2] - mu) * rstd * gg.z + bb.z;  v.z = v.z >= 0.f ? v.z : p0 * v.z;
            v.w = (vv[i2 * 4 + 3] - mu) * rstd * gg.w + bb.w;  v.w = v.w >= 0.f ? v.w : p0 * v.w;
            *(uint2*)&S[r * P + c4 * 4] = pack4(v);
          }
        } else {     // f32 input (x)
          const float4* srcp = (const float4*)((const float*)act + (size_t)node * FI);
          #pragma unroll
          for (int i = 0; i < FI / 16; ++i) {
            const int c = (tid & 3) * (FI / 4) + i * 4;
            const float4 v = srcp[c >> 2];
            *(uint2*)&S[r * P + c] = pack4(v);
          }
        }
      }
    }
    __syncthreads();

    const f32x4 fz = {0.f, 0.f, 0.f, 0.f};
    f32x4 acc[4]; acc[0] = fz; acc[1] = fz; acc[2] = fz; acc[3] = fz;
    #pragma unroll
    for (int kt = 0; kt < FI / 32; ++kt) {
      const bf16x8 Af = *(const bf16x8*)&S[(wid * 16 + l15) * P + kt * 32 + lhi * 8];
      #pragma unroll
      for (int nt = 0; nt < 4; ++nt)
        acc[nt] = __builtin_amdgcn_mfma_f32_16x16x32_bf16(Af, Bf[kt][nt], acc[nt], 0, 0, 0);
    }
    #pragma unroll
    for (int r = 0; r < 4; ++r) {
      float ps = acc[0][r] * asf[0] + acc[1][r] * asf[1] + acc[2][r] * asf[2] + acc[3][r] * asf[3];
      float pd = acc[0][r] * adf[0] + acc[1][r] * adf[1] + acc[2][r] * adf[2] + acc[3][r] * adf[3];
      #pragma unroll
      for (int off = 1; off < 16; off <<= 1) { ps += __shfl_xor(ps, off); pd += __shfl_xor(pd, off); }
      const int node = nb + wid * 16 + lhi * 4 + r;
      if (l15 == 0 && node < N) { hs[node] = ps; hd[node] = pd; }
    }
    #pragma unroll
    for (int nt = 0; nt < 4; ++nt)
      #pragma unroll
      for (int r = 0; r < 4; ++r)
        S[(wid * 16 + lhi * 4 + r) * P + nt * 16 + l15] = f2b(acc[nt][r]);
    __syncthreads();
    {
      const int r = tid >> 2, chunk = tid & 3;
      const int node = nb + r;
      if (node < N) {
        const int4* sp = (const int4*)&S[r * P + chunk * 16];
        const int4 v0 = sp[0], v1 = sp[1];
        int4* dp = (int4*)(h16 + (size_t)node * 64 + chunk * 16);
        dp[0] = v0; dp[1] = v1;
      }
    }
    __syncthreads();
  }
}

// ---------------- GAT aggregation: y_i = (sum_j w_j h_j + w_self h_i)/z + bias ----
// Chunk = 32 edges, static issue/consume split (measured floor ~62us across 3
// structural variants; FETCH ~= 8 XCD x |h16| = structural minimum for random
// graphs). y written as bf16. Graph-LN (sum, sumsq) accumulated via 2 atomics
// per block spread over 128 line-padded slots (R11 lesson: 2 same-line targets
// serialized 50K atomics at ~12ns each -> +580us; 128 lines -> ~5us, hidden).
__global__ __launch_bounds__(256) void k_aggregate(
    const int* __restrict__ rs, const int* __restrict__ re, const int* __restrict__ csr,
    const ushort_t* __restrict__ h16, const float* __restrict__ hs, const float* __restrict__ hd,
    const float* __restrict__ bias, int N,
    ushort_t* __restrict__ y16, float* __restrict__ statsOut)
{
  __shared__ float wsh[4][32];
  __shared__ float sh1[4], sh2[4];
  const int tid = threadIdx.x, wid = tid >> 6, lane = tid & 63;
  const int node = blockIdx.x * 4 + wid;
  float val = 0.f;
  if (node < N) {
    const float hdi = hd[node];
    const float wself = __expf(lrelu(hs[node] + hdi));   // self loop
    float z = wself;
    float acc0 = wself * b2f(h16[((size_t)(uint32_t)node << 6) + lane]);
    float acc1 = 0.f, acc2 = 0.f, acc3 = 0.f;
    const int st = __builtin_amdgcn_readfirstlane(rs[node]);
    const int en = __builtin_amdgcn_readfirstlane(re[node]);
    for (int j = st; j < en; j += 32) {
      const int m = min(32, en - j);
      int sA = 0;
      if (lane < m) sA = csr[j + lane];
      // ---- issue gathers (4-granular) ----
      #define GA(u) h16[((size_t)(uint32_t)__builtin_amdgcn_readlane(sA, u) << 6) + lane]
      ushort_t g0 = 0, g1 = 0, g2 = 0, g3 = 0, g4 = 0, g5 = 0, g6 = 0, g7 = 0;
      ushort_t g8 = 0, g9 = 0, g10 = 0, g11 = 0, g12 = 0, g13 = 0, g14 = 0, g15 = 0;
      ushort_t g16 = 0, g17 = 0, g18 = 0, g19 = 0, g20 = 0, g21 = 0, g22 = 0, g23 = 0;
      ushort_t g24 = 0, g25 = 0, g26 = 0, g27 = 0, g28 = 0, g29 = 0, g30 = 0, g31 = 0;
      if (m > 0)  { g0  = GA(0);  g1  = GA(1);  g2  = GA(2);  g3  = GA(3);  }
      if (m > 4)  { g4  = GA(4);  g5  = GA(5);  g6  = GA(6);  g7  = GA(7);  }
      if (m > 8)  { g8  = GA(8);  g9  = GA(9);  g10 = GA(10); g11 = GA(11); }
      if (m > 12) { g12 = GA(12); g13 = GA(13); g14 = GA(14); g15 = GA(15); }
      if (m > 16) { g16 = GA(16); g17 = GA(17); g18 = GA(18); g19 = GA(19); }
      if (m > 20) { g20 = GA(20); g21 = GA(21); g22 = GA(22); g23 = GA(23); }
      if (m > 24) { g24 = GA(24); g25 = GA(25); g26 = GA(26); g27 = GA(27); }
      if (m > 28) { g28 = GA(28); g29 = GA(29); g30 = GA(30); g31 = GA(31); }
      #undef GA
      // ---- weights (overlap with gather latency) ----
      float wA = 0.f;
      if (lane < m) wA = __expf(lrelu(hs[sA] + hdi));
      if (lane < 32) wsh[wid][lane] = wA;    // full 32 slots (0-padded)
      float ws = wA;
      #pragma unroll
      for (int off = 32; off; off >>= 1) ws += __shfl_xor(ws, off);
      z += ws;
      // ---- consume ----
      #define CS(u, a) a = fmaf(wsh[wid][u], b2f(g##u), a)
      if (m > 0)  { CS(0, acc0);  CS(1, acc1);  CS(2, acc2);  CS(3, acc3);  }
      if (m > 4)  { CS(4, acc0);  CS(5, acc1);  CS(6, acc2);  CS(7, acc3);  }
      if (m > 8)  { CS(8, acc0);  CS(9, acc1);  CS(10, acc2); CS(11, acc3); }
      if (m > 12) { CS(12, acc0); CS(13, acc1); CS(14, acc2); CS(15, acc3); }
      if (m > 16) { CS(16, acc0); CS(17, acc1); CS(18, acc2); CS(19, acc3); }
      if (m > 20) { CS(20, acc0); CS(21, acc1); CS(22, acc2); CS(23, acc3); }
      if (m > 24) { CS(24, acc0); CS(25, acc1); CS(26, acc2); CS(27, acc3); }
      if (m > 28) { CS(28, acc0); CS(29, acc1); CS(30, acc2); CS(31, acc3); }
      #undef CS
    }
    val = ((acc0 + acc1) + (acc2 + acc3)) / z + bias[lane];
    y16[(size_t)node * 64 + lane] = f2b(val);
  }
  float s1r = val, s2r = val * val;
  #pragma unroll
  for (int off = 32; off; off >>= 1) { s1r += __shfl_xor(s1r, off); s2r += __shfl_xor(s2r, off); }
  if (lane == 0) { sh1[wid] = s1r; sh2[wid] = s2r; }
  __syncthreads();
  if (tid == 0) {
    float* slot = statsOut + (size_t)(blockIdx.x & (NSLOT - 1)) * SLOTF;
    atomicAdd(&slot[0], sh1[0] + sh1[1] + sh1[2] + sh1[3]);
    atomicAdd(&slot[1], sh2[0] + sh2[1] + sh2[2] + sh2[3]);
  }
}

// ---------------- MLP head (MFMA): out = prelu(LN(y) @ W1 + b1) @ W2 + b2 -------
__global__ __launch_bounds__(256) void k_mlp(
    const ushort_t* __restrict__ y16, int N,
    const float* __restrict__ stats, float invCount, const float* __restrict__ g,
    const float* __restrict__ be, const float* __restrict__ pe,
    const float* __restrict__ W1, const float* __restrict__ b1, const float* __restrict__ pm,
    const float* __restrict__ W2, const float* __restrict__ b2,
    float* __restrict__ outp)
{
  __shared__ ushort_t W1t[128 * 72];   // W1^T bf16 [f=128][k=64],  pitch 72
  __shared__ ushort_t W2t[64 * 136];   // W2^T bf16 [f=64][k=128],  pitch 136
  __shared__ ushort_t At[64 * 72];     // LN(y) tile bf16
  __shared__ ushort_t Tt[64 * 136];    // hidden tile bf16
  __shared__ float    Ob[64 * 68];     // out tile f32
  const int tid = threadIdx.x, wid = tid >> 6, lane = tid & 63;
  const int l15 = lane & 15, lhi = lane >> 4;

  for (int idx = tid; idx < 64 * 128; idx += 256) {   // W1 [64][128]
    const int k = idx >> 7, f = idx & 127;
    W1t[f * 72 + k] = f2b(W1[idx]);
  }
  for (int idx = tid; idx < 128 * 64; idx += 256) {   // W2 [128][64]
    const int k = idx >> 6, f = idx & 63;
    W2t[f * 136 + k] = f2b(W2[idx]);
  }
  __syncthreads();

  float mu, rstd;
  ln_from_slots(stats, invCount, mu, rstd);
  const float p0 = pe[0], pm0 = pm[0];
  float b1f[8], b2f_[4];
  #pragma unroll
  for (int nt = 0; nt < 8; ++nt) b1f[nt] = b1[nt * 16 + l15];
  #pragma unroll
  for (int nt = 0; nt < 4; ++nt) b2f_[nt] = b2[nt * 16 + l15];

  const int ntiles = (N + 63) >> 6;
  for (int tile = blockIdx.x; tile < ntiles; tile += gridDim.x) {
    const int nb = tile << 6;
    {   // stage LN(y)+prelu tile from bf16 y
      const int r = tid >> 2;
      const int node = nb + r;
      if (node < N) {
        const int q = tid & 3;
        const int4* srcp = (const int4*)(y16 + (size_t)node * 64 + q * 16);
        const int4 A0 = srcp[0], A1 = srcp[1];
        const ushort_t* pu0 = (const ushort_t*)&A0;
        const ushort_t* pu1 = (const ushort_t*)&A1;
        float vv[16];
        #pragma unroll
        for (int i = 0; i < 8; ++i) { vv[i] = b2f(pu0[i]); vv[8 + i] = b2f(pu1[i]); }
        #pragma unroll
        for (int i2 = 0; i2 < 4; ++i2) {
          const int c4 = q * 4 + i2;
          const float4 gg = ((const float4*)g)[c4];
          const float4 bb = ((const float4*)be)[c4];
          float4 v;
          v.x = (vv[i2 * 4 + 0] - mu) * rstd * gg.x + bb.x;  v.x = v.x >= 0.f ? v.x : p0 * v.x;
          v.y = (vv[i2 * 4 + 1] - mu) * rstd * gg.y + bb.y;  v.y = v.y >= 0.f ? v.y : p0 * v.y;
          v.z = (vv[i2 * 4 + 2] - mu) * rstd * gg.z + bb.z;  v.z = v.z >= 0.f ? v.z : p0 * v.z;
          v.w = (vv[i2 * 4 + 3] - mu) * rstd * gg.w + bb.w;  v.w = v.w >= 0.f ? v.w : p0 * v.w;
          *(uint2*)&At[r * 72 + c4 * 4] = pack4(v);
        }
      }
    }
    __syncthreads();

    const f32x4 fz = {0.f, 0.f, 0.f, 0.f};
    f32x4 acc1[8];
    #pragma unroll
    for (int nt = 0; nt < 8; ++nt) acc1[nt] = fz;
    #pragma unroll
    for (int kt = 0; kt < 2; ++kt) {
      const bf16x8 Af = *(const bf16x8*)&At[(wid * 16 + l15) * 72 + kt * 32 + lhi * 8];
      #pragma unroll
      for (int nt = 0; nt < 8; ++nt) {
        const bf16x8 Bf = *(const bf16x8*)&W1t[(nt * 16 + l15) * 72 + kt * 32 + lhi * 8];
        acc1[nt] = __builtin_amdgcn_mfma_f32_16x16x32_bf16(Af, Bf, acc1[nt], 0, 0, 0);
      }
    }
    #pragma unroll
    for (int nt = 0; nt < 8; ++nt)
      #pragma unroll
      for (int r = 0; r < 4; ++r) {
        float v = acc1[nt][r] + b1f[nt];
        v = v >= 0.f ? v : pm0 * v;
        Tt[(wid * 16 + lhi * 4 + r) * 136 + nt * 16 + l15] = f2b(v);
      }
    __syncthreads();

    f32x4 acc2[4];
    #pragma unroll
    for (int nt = 0; nt < 4; ++nt) acc2[nt] = fz;
    #pragma unroll
    for (int kt = 0; kt < 4; ++kt) {
      const bf16x8 Af = *(const bf16x8*)&Tt[(wid * 16 + l15) * 136 + kt * 32 + lhi * 8];
      #pragma unroll
      for (int nt = 0; nt < 4; ++nt) {
        const bf16x8 Bf = *(const bf16x8*)&W2t[(nt * 16 + l15) * 136 + kt * 32 + lhi * 8];
        acc2[nt] = __builtin_amdgcn_mfma_f32_16x16x32_bf16(Af, Bf, acc2[nt], 0, 0, 0);
      }
    }
    #pragma unroll
    for (int nt = 0; nt < 4; ++nt)
      #pragma unroll
      for (int r = 0; r < 4; ++r)
        Ob[(wid * 16 + lhi * 4 + r) * 68 + nt * 16 + l15] = acc2[nt][r] + b2f_[nt];
    __syncthreads();
    {
      const int r = tid >> 2, chunk = tid & 3;
      const int node = nb + r;
      if (node < N) {
        const float4* sp = (const float4*)&Ob[r * 68 + chunk * 16];
        const float4 v0 = sp[0], v1 = sp[1], v2 = sp[2], v3 = sp[3];
        float4* dp = (float4*)(outp + (size_t)node * 64 + chunk * 16);
        dp[0] = v0; dp[1] = v1; dp[2] = v2; dp[3] = v3;
      }
    }
    __syncthreads();
  }
}

// ---------------- K-encoder final LN+PReLU (bf16 y -> f32 out) ------------------
__global__ void k_ln_prelu_out(const ushort_t* __restrict__ y16, int total8,
                               const float* __restrict__ stats, float invCount,
                               const float* __restrict__ g,
                               const float* __restrict__ be, const float* __restrict__ pe,
                               float* __restrict__ o)
{
  float mu, rstd;
  ln_from_slots(stats, invCount, mu, rstd);
  const float p0 = pe[0];
  int i = blockIdx.x * blockDim.x + threadIdx.x;
  const int stride = gridDim.x * blockDim.x;
  for (; i < total8; i += stride) {
    const int4 A = *(const int4*)(y16 + (size_t)i * 8);
    const ushort_t* pu = (const ushort_t*)&A;
    const int grp = i & 7;
    const float4 g0 = ((const float4*)g)[grp * 2], g1 = ((const float4*)g)[grp * 2 + 1];
    const float4 b0 = ((const float4*)be)[grp * 2], b1 = ((const float4*)be)[grp * 2 + 1];
    float4 o0, o1;
    o0.x = (b2f(pu[0]) - mu) * rstd * g0.x + b0.x;  o0.x = o0.x >= 0.f ? o0.x : p0 * o0.x;
    o0.y = (b2f(pu[1]) - mu) * rstd * g0.y + b0.y;  o0.y = o0.y >= 0.f ? o0.y : p0 * o0.y;
    o0.z = (b2f(pu[2]) - mu) * rstd * g0.z + b0.z;  o0.z = o0.z >= 0.f ? o0.z : p0 * o0.z;
    o0.w = (b2f(pu[3]) - mu) * rstd * g0.w + b0.w;  o0.w = o0.w >= 0.f ? o0.w : p0 * o0.w;
    o1.x = (b2f(pu[4]) - mu) * rstd * g1.x + b1.x;  o1.x = o1.x >= 0.f ? o1.x : p0 * o1.x;
    o1.y = (b2f(pu[5]) - mu) * rstd * g1.y + b1.y;  o1.y = o1.y >= 0.f ? o1.y : p0 * o1.y;
    o1.z = (b2f(pu[6]) - mu) * rstd * g1.z + b1.z;  o1.z = o1.z >= 0.f ? o1.z : p0 * o1.z;
    o1.w = (b2f(pu[7]) - mu) * rstd * g1.w + b1.w;  o1.w = o1.w >= 0.f ? o1.w : p0 * o1.w;
    float4* dp = (float4*)(o + (size_t)i * 8);
    dp[0] = o0; dp[1] = o1;
  }
}

// ================================================================================
extern "C" void kernel_launch(void* const* d_in, const int* in_sizes, int n_in,
                              void* d_out, int out_size, void* d_ws, size_t ws_size,
                              hipStream_t stream) {
  (void)n_in; (void)out_size; (void)ws_size;
  const int FIN = 128, F = 64;
  const int N = in_sizes[0] / FIN;
  const int E = in_sizes[2] / 2;

  const float* x_q = (const float*)d_in[0];
  const float* x_k = (const float*)d_in[1];
  const int*   ei_q = (const int*)d_in[2];
  const int*   ei_k = (const int*)d_in[3];
  const float* L[4][7];
  for (int l = 0; l < 4; ++l)
    for (int j = 0; j < 7; ++j) L[l][j] = (const float*)d_in[4 + l * 7 + j];
  const float* mW1 = (const float*)d_in[32];
  const float* mb1 = (const float*)d_in[33];
  const float* mp  = (const float*)d_in[34];
  const float* mW2 = (const float*)d_in[35];
  const float* mb2 = (const float*)d_in[36];
  float* out = (float*)d_out;

  const int CAP = (((E + NBUK - 1) / NBUK) * 3 / 2 + 3) & ~3;   // 1.5x mean bucket fill

  char* w = (char*)d_ws;
  auto alloc = [&](size_t bytes) { char* r = w; w += (bytes + 255) & ~size_t(255); return r; };
  ushort_t* h16 = (ushort_t*)alloc((size_t)N * F * sizeof(ushort_t));
  ushort_t* y16 = (ushort_t*)alloc((size_t)N * F * sizeof(ushort_t));
  float* hs    = (float*)alloc((size_t)N * sizeof(float));
  float* hd    = (float*)alloc((size_t)N * sizeof(float));
  float* stats = (float*)alloc(4 * NSLOT * SLOTF * sizeof(float));  // 4 layers x 128 line-padded slots
  int* rs      = (int*)alloc((size_t)N * sizeof(int));
  int* re      = (int*)alloc((size_t)N * sizeof(int));
  int* csr     = (int*)alloc((size_t)NBUK * CAP * sizeof(int));
  int* bcur    = (int*)alloc(NBUK * sizeof(int));
  int2* pairs  = (int2*)alloc((size_t)NBUK * CAP * sizeof(int2));

  const float invCount = 1.f / ((float)N * (float)F);
  const uint32_t bmul = (uint32_t)(((uint64_t)NBUK << 32) / (uint64_t)N);
  const int nblk = (N + 3) / 4;
  const int ntiles = (N + 63) / 64;
  const int nchunkE = (E + 4095) >> 12;
  const int LSTRIDE = NSLOT * SLOTF;

  hipMemsetAsync(stats, 0, 4 * NSLOT * SLOTF * sizeof(float), stream);

  auto build_csr = [&](const int* ei) {
    kb_init<<<1, NBUK, 0, stream>>>(bcur, CAP);
    kb_expand<<<nchunkE, 256, 0, stream>>>(ei, ei + E, E, bcur, pairs, bmul);
    kb_sort<<<NBUK, 256, 0, stream>>>(pairs, bcur, rs, re, csr, bmul, CAP, N);
  };

  auto run_layers = [&](const float* x0, int li0) {
    const float* const* A = L[li0];
    k_gemm_att<128, false><<<ntiles, 256, 0, stream>>>(
        x0, N, A[0], A[1], A[2], nullptr, 0.f, nullptr, nullptr, nullptr, h16, hs, hd);
    k_aggregate<<<nblk, 256, 0, stream>>>(rs, re, csr, h16, hs, hd, A[3], N, y16,
                                          stats + (size_t)li0 * LSTRIDE);
    const float* const* B = L[li0 + 1];
    k_gemm_att<64, true><<<ntiles, 256, 0, stream>>>(
        y16, N, B[0], B[1], B[2], stats + (size_t)li0 * LSTRIDE, invCount,
        A[4], A[5], A[6], h16, hs, hd);
    k_aggregate<<<nblk, 256, 0, stream>>>(rs, re, csr, h16, hs, hd, B[3], N, y16,
                                          stats + (size_t)(li0 + 1) * LSTRIDE);
  };

  // ---- Q path ----
  build_csr(ei_q);
  run_layers(x_q, 0);
  k_mlp<<<512, 256, 0, stream>>>(y16, N, stats + (size_t)1 * LSTRIDE, invCount,
                                 L[1][4], L[1][5], L[1][6],
                                 mW1, mb1, mp, mW2, mb2, out);

  // ---- K path (reuses all scratch) ----
  build_csr(ei_k);
  run_layers(x_k, 2);
  const int total8 = N * F / 8;
  k_ln_prelu_out<<<2048, 256, 0, stream>>>(y16, total8, stats + (size_t)3 * LSTRIDE, invCount,
                                           L[3][4], L[3][5], L[3][6],
                                           out + (size_t)N * F);
}

// Round 13
// 398.945 us; speedup vs baseline: 6.9244x; 1.1717x over previous
//
#include <hip/hip_runtime.h>
#include <cstddef>
#include <cstdint>

#define NEG_SLOPE 0.2f
#define LN_EPS    1e-5f
#define NBUK      256      // buckets for CSR counting sort
#define MAXNPB    512      // max nodes per bucket (LDS histogram size)

typedef unsigned short ushort_t;
typedef short bf16x8 __attribute__((ext_vector_type(8)));
typedef float f32x4  __attribute__((ext_vector_type(4)));

__device__ __forceinline__ float lrelu(float s) { return s >= 0.f ? s : NEG_SLOPE * s; }
__device__ __forceinline__ float b2f(ushort_t u) { return __uint_as_float(((uint32_t)u) << 16); }
__device__ __forceinline__ ushort_t f2b(float f) {   // round-to-nearest-even (finite inputs)
  uint32_t u = __float_as_uint(f);
  return (ushort_t)((u + 0x7fffu + ((u >> 16) & 1u)) >> 16);
}
__device__ __forceinline__ uint2 pack4(float4 v) {
  uint2 r;
  r.x = (uint32_t)f2b(v.x) | ((uint32_t)f2b(v.y) << 16);
  r.y = (uint32_t)f2b(v.z) | ((uint32_t)f2b(v.w) << 16);
  return r;
}

// ============== CSR build: single-pass bucketed counting sort, Q||K fused ==========
__global__ void kb_init(int* __restrict__ b0, int* __restrict__ b1, int cap) {
  b0[threadIdx.x] = threadIdx.x * cap;
  b1[threadIdx.x] = threadIdx.x * cap;
}

__global__ __launch_bounds__(256) void kb_expand(
    const int* __restrict__ ei0, const int* __restrict__ ei1, int E, int nchunk,
    int* __restrict__ bcur0, int* __restrict__ bcur1,
    int2* __restrict__ pairs0, int2* __restrict__ pairs1, uint32_t bmul) {
  __shared__ int hist[NBUK], base[NBUK], lcnt[NBUK];
  const int tid = threadIdx.x;
  const int path = (blockIdx.x >= (unsigned)nchunk) ? 1 : 0;
  const int c = blockIdx.x - path * nchunk;
  const int* src = path ? ei1 : ei0;
  const int* dst = src + E;
  int* gbcur = path ? bcur1 : bcur0;
  int2* pairs = path ? pairs1 : pairs0;

  const int e0 = c << 12;
  hist[tid] = 0; lcnt[tid] = 0;
  __syncthreads();
  int sv[16], dv[16], bv[16];
  #pragma unroll
  for (int u = 0; u < 16; ++u) {
    const int i = e0 + u * 256 + tid;
    if (i < E) {
      sv[u] = src[i]; dv[u] = dst[i];
      bv[u] = (int)__umulhi((uint32_t)dv[u], bmul);
      atomicAdd(&hist[bv[u]], 1);
    } else bv[u] = -1;
  }
  __syncthreads();
  base[tid] = atomicAdd(&gbcur[tid], hist[tid]);
  __syncthreads();
  #pragma unroll
  for (int u = 0; u < 16; ++u) {
    if (bv[u] >= 0) {
      const int pos = atomicAdd(&lcnt[bv[u]], 1);
      pairs[base[bv[u]] + pos] = make_int2(sv[u], dv[u]);
    }
  }
}

__global__ __launch_bounds__(256) void kb_sort(
    const int2* __restrict__ pairs0, const int2* __restrict__ pairs1,
    const int* __restrict__ bcur0, const int* __restrict__ bcur1,
    int* __restrict__ rs0, int* __restrict__ rs1,
    int* __restrict__ re0, int* __restrict__ re1,
    int* __restrict__ csr0, int* __restrict__ csr1,
    uint32_t bmul, int cap, int N) {
  __shared__ int hist[MAXNPB];
  __shared__ int ps[256];
  const int path = (blockIdx.x >= NBUK) ? 1 : 0;
  const int b = blockIdx.x & (NBUK - 1);
  const int tid = threadIdx.x;
  const int2* pairs = path ? pairs1 : pairs0;
  const int* gbcur = path ? bcur1 : bcur0;
  int* rs = path ? rs1 : rs0;
  int* re = path ? re1 : re0;
  int* csr = path ? csr1 : csr0;

  int n0 = (int)((((uint64_t)b << 32) + bmul - 1) / bmul);
  int n1 = (int)((((uint64_t)(b + 1) << 32) + bmul - 1) / bmul);
  n0 = n0 < N ? n0 : N;
  n1 = n1 < N ? n1 : N;
  const int nn = n1 - n0;
  const int e0 = b * cap;
  const int e1 = min(gbcur[b], e0 + cap);
  for (int k = tid; k < nn; k += 256) hist[k] = 0;
  __syncthreads();
  for (int i = e0 + tid; i < e1; i += 256) atomicAdd(&hist[pairs[i].y - n0], 1);
  __syncthreads();
  const int i0 = 2 * tid, i1 = 2 * tid + 1;
  const int a = (i0 < nn) ? hist[i0] : 0;
  const int c = (i1 < nn) ? hist[i1] : 0;
  const int tot = a + c;
  ps[tid] = tot;
  __syncthreads();
  for (int off = 1; off < 256; off <<= 1) {
    const int x = (tid >= off) ? ps[tid - off] : 0;
    __syncthreads();
    ps[tid] += x;
    __syncthreads();
  }
  const int excl = ps[tid] - tot;
  if (i0 < nn) { hist[i0] = excl;     rs[n0 + i0] = e0 + excl;     re[n0 + i0] = e0 + excl + a; }
  if (i1 < nn) { hist[i1] = excl + a; rs[n0 + i1] = e0 + excl + a; re[n0 + i1] = e0 + excl + a + c; }
  __syncthreads();
  for (int i = e0 + tid; i < e1; i += 256) {
    const int2 e = pairs[i];
    const int p = atomicAdd(&hist[e.y - n0], 1);
    csr[e0 + p] = e.x;
  }
}

// ---------------- MFMA GEMM (h = act @ W) + attention dots, Q||K fused ----------
// act f32 for layer 1 (LNF=false), bf16 for layer 2 (LNF=true; stats = {mu,rstd}).
template <int FI, bool LNF>
__global__ __launch_bounds__(256) void k_gemm_att(
    const void* __restrict__ act0, const void* __restrict__ act1, int N, int ntiles,
    const float* __restrict__ W0, const float* __restrict__ W1x,
    const float* __restrict__ as0, const float* __restrict__ as1,
    const float* __restrict__ ad0, const float* __restrict__ ad1,
    const float* __restrict__ st0, const float* __restrict__ st1,
    const float* __restrict__ g0, const float* __restrict__ g1,
    const float* __restrict__ be0, const float* __restrict__ be1,
    const float* __restrict__ pp0, const float* __restrict__ pp1,
    ushort_t* __restrict__ h0, ushort_t* __restrict__ h1,
    float* __restrict__ hs0, float* __restrict__ hs1,
    float* __restrict__ hd0, float* __restrict__ hd1)
{
  constexpr int P = FI + 8;                 // bf16 row pitch: +16B pad -> 4-bank rotation
  __shared__ ushort_t S[64 * P];            // Wt stage, then act tile / out tile
  const int tid = threadIdx.x, wid = tid >> 6, lane = tid & 63;
  const int l15 = lane & 15, lhi = lane >> 4;

  const int path = (blockIdx.x >= (unsigned)ntiles) ? 1 : 0;
  const int tile = blockIdx.x - path * ntiles;
  const void* act = path ? act1 : act0;
  const float* W  = path ? W1x : W0;
  const float* a_s = path ? as1 : as0;
  const float* a_d = path ? ad1 : ad0;
  const float* stats = path ? st1 : st0;
  const float* g  = path ? g1 : g0;
  const float* be = path ? be1 : be0;
  const float* pp = path ? pp1 : pp0;
  ushort_t* h16 = path ? h1 : h0;
  float* hs = path ? hs1 : hs0;
  float* hd = path ? hd1 : hd0;

  for (int idx = tid; idx < FI * 64; idx += 256) {
    const int k = idx >> 6, f = idx & 63;
    S[f * P + k] = f2b(W[idx]);
  }
  __syncthreads();
  bf16x8 Bf[FI / 32][4];
  #pragma unroll
  for (int kt = 0; kt < FI / 32; ++kt)
    #pragma unroll
    for (int nt = 0; nt < 4; ++nt)
      Bf[kt][nt] = *(const bf16x8*)&S[(nt * 16 + l15) * P + kt * 32 + lhi * 8];
  __syncthreads();

  float asf[4], adf[4];
  #pragma unroll
  for (int nt = 0; nt < 4; ++nt) { asf[nt] = a_s[nt * 16 + l15]; adf[nt] = a_d[nt * 16 + l15]; }
  float mu = 0.f, rstd = 1.f, p0 = 0.f;
  if (LNF) { mu = stats[0]; rstd = stats[1]; p0 = pp[0]; }

  const int nb = tile << 6;
  {   // stage activation tile -> bf16 LDS
    const int r = tid >> 2;
    const int node = nb + r;
    if (node < N) {
      if (LNF) {   // bf16 input (aggregated y), fuse LN+PReLU
        const ushort_t* a16 = (const ushort_t*)act;
        const int q = tid & 3;   // 16-feature chunk
        const int4* srcp = (const int4*)(a16 + (size_t)node * 64 + q * 16);
        const int4 A0 = srcp[0], A1 = srcp[1];
        const ushort_t* pu0 = (const ushort_t*)&A0;
        const ushort_t* pu1 = (const ushort_t*)&A1;
        float vv[16];
        #pragma unroll
        for (int i = 0; i < 8; ++i) { vv[i] = b2f(pu0[i]); vv[8 + i] = b2f(pu1[i]); }
        #pragma unroll
        for (int i2 = 0; i2 < 4; ++i2) {
          const int c4 = q * 4 + i2;
          const float4 gg = ((const float4*)g)[c4];
          const float4 bb = ((const float4*)be)[c4];
          float4 v;
          v.x = (vv[i2 * 4 + 0] - mu) * rstd * gg.x + bb.x;  v.x = v.x >= 0.f ? v.x : p0 * v.x;
          v.y = (vv[i2 * 4 + 1] - mu) * rstd * gg.y + bb.y;  v.y = v.y >= 0.f ? v.y : p0 * v.y;
          v.z = (vv[i2 * 4 + 2] - mu) * rstd * gg.z + bb.z;  v.z = v.z >= 0.f ? v.z : p0 * v.z;
          v.w = (vv[i2 * 4 + 3] - mu) * rstd * gg.w + bb.w;  v.w = v.w >= 0.f ? v.w : p0 * v.w;
          *(uint2*)&S[r * P + c4 * 4] = pack4(v);
        }
      } else {     // f32 input (x)
        const float4* srcp = (const float4*)((const float*)act + (size_t)node * FI);
        #pragma unroll
        for (int i = 0; i < FI / 16; ++i) {
          const int c = (tid & 3) * (FI / 4) + i * 4;
          const float4 v = srcp[c >> 2];
          *(uint2*)&S[r * P + c] = pack4(v);
        }
      }
    }
  }
  __syncthreads();

  const f32x4 fz = {0.f, 0.f, 0.f, 0.f};
  f32x4 acc[4]; acc[0] = fz; acc[1] = fz; acc[2] = fz; acc[3] = fz;
  #pragma unroll
  for (int kt = 0; kt < FI / 32; ++kt) {
    const bf16x8 Af = *(const bf16x8*)&S[(wid * 16 + l15) * P + kt * 32 + lhi * 8];
    #pragma unroll
    for (int nt = 0; nt < 4; ++nt)
      acc[nt] = __builtin_amdgcn_mfma_f32_16x16x32_bf16(Af, Bf[kt][nt], acc[nt], 0, 0, 0);
  }
  #pragma unroll
  for (int r = 0; r < 4; ++r) {
    float ps = acc[0][r] * asf[0] + acc[1][r] * asf[1] + acc[2][r] * asf[2] + acc[3][r] * asf[3];
    float pd = acc[0][r] * adf[0] + acc[1][r] * adf[1] + acc[2][r] * adf[2] + acc[3][r] * adf[3];
    #pragma unroll
    for (int off = 1; off < 16; off <<= 1) { ps += __shfl_xor(ps, off); pd += __shfl_xor(pd, off); }
    const int node = nb + wid * 16 + lhi * 4 + r;
    if (l15 == 0 && node < N) { hs[node] = ps; hd[node] = pd; }
  }
  #pragma unroll
  for (int nt = 0; nt < 4; ++nt)
    #pragma unroll
    for (int r = 0; r < 4; ++r)
      S[(wid * 16 + lhi * 4 + r) * P + nt * 16 + l15] = f2b(acc[nt][r]);
  __syncthreads();
  {
    const int r = tid >> 2, chunk = tid & 3;
    const int node = nb + r;
    if (node < N) {
      const int4* sp = (const int4*)&S[r * P + chunk * 16];
      const int4 v0 = sp[0], v1 = sp[1];
      int4* dp = (int4*)(h16 + (size_t)node * 64 + chunk * 16);
      dp[0] = v0; dp[1] = v1;
    }
  }
}

// ---------------- GAT aggregation, Q||K fused ----------------------------------
// Chunk = 32 edges, static issue/consume split (measured floor ~62us across 3
// structural variants; FETCH ~= 8 XCD x |h16| = structural minimum for random
// graphs). y written as bf16; per-block (sum,sumsq) -> part[] (R10 scheme —
// R11/R12 lesson: contended or even slot-spread atomics cost more than the
// separate 1-block reduce kernel).
__global__ __launch_bounds__(256) void k_aggregate(
    const int* __restrict__ rs0, const int* __restrict__ rs1,
    const int* __restrict__ re0, const int* __restrict__ re1,
    const int* __restrict__ csr0, const int* __restrict__ csr1,
    const ushort_t* __restrict__ h0, const ushort_t* __restrict__ h1,
    const float* __restrict__ hs0, const float* __restrict__ hs1,
    const float* __restrict__ hd0, const float* __restrict__ hd1,
    const float* __restrict__ bias0, const float* __restrict__ bias1,
    int N, int nblk,
    ushort_t* __restrict__ y0, ushort_t* __restrict__ y1,
    float* __restrict__ part0, float* __restrict__ part1)
{
  __shared__ float wsh[4][32];
  __shared__ float sh1[4], sh2[4];
  const int tid = threadIdx.x, wid = tid >> 6, lane = tid & 63;
  const int path = (blockIdx.x >= (unsigned)nblk) ? 1 : 0;
  const int bb = blockIdx.x - path * nblk;
  const int* rs = path ? rs1 : rs0;
  const int* re = path ? re1 : re0;
  const int* csr = path ? csr1 : csr0;
  const ushort_t* h16 = path ? h1 : h0;
  const float* hs = path ? hs1 : hs0;
  const float* hd = path ? hd1 : hd0;
  const float* bias = path ? bias1 : bias0;
  ushort_t* y16 = path ? y1 : y0;
  float* part = path ? part1 : part0;

  const int node = bb * 4 + wid;
  float val = 0.f;
  if (node < N) {
    const float hdi = hd[node];
    const float wself = __expf(lrelu(hs[node] + hdi));   // self loop
    float z = wself;
    float acc0 = wself * b2f(h16[((size_t)(uint32_t)node << 6) + lane]);
    float acc1 = 0.f, acc2 = 0.f, acc3 = 0.f;
    const int st = __builtin_amdgcn_readfirstlane(rs[node]);
    const int en = __builtin_amdgcn_readfirstlane(re[node]);
    for (int j = st; j < en; j += 32) {
      const int m = min(32, en - j);
      int sA = 0;
      if (lane < m) sA = csr[j + lane];
      // ---- issue gathers (4-granular) ----
      #define GA(u) h16[((size_t)(uint32_t)__builtin_amdgcn_readlane(sA, u) << 6) + lane]
      ushort_t g0 = 0, g1 = 0, g2 = 0, g3 = 0, g4 = 0, g5 = 0, g6 = 0, g7 = 0;
      ushort_t g8 = 0, g9 = 0, g10 = 0, g11 = 0, g12 = 0, g13 = 0, g14 = 0, g15 = 0;
      ushort_t g16 = 0, g17 = 0, g18 = 0, g19 = 0, g20 = 0, g21 = 0, g22 = 0, g23 = 0;
      ushort_t g24 = 0, g25 = 0, g26 = 0, g27 = 0, g28 = 0, g29 = 0, g30 = 0, g31 = 0;
      if (m > 0)  { g0  = GA(0);  g1  = GA(1);  g2  = GA(2);  g3  = GA(3);  }
      if (m > 4)  { g4  = GA(4);  g5  = GA(5);  g6  = GA(6);  g7  = GA(7);  }
      if (m > 8)  { g8  = GA(8);  g9  = GA(9);  g10 = GA(10); g11 = GA(11); }
      if (m > 12) { g12 = GA(12); g13 = GA(13); g14 = GA(14); g15 = GA(15); }
      if (m > 16) { g16 = GA(16); g17 = GA(17); g18 = GA(18); g19 = GA(19); }
      if (m > 20) { g20 = GA(20); g21 = GA(21); g22 = GA(22); g23 = GA(23); }
      if (m > 24) { g24 = GA(24); g25 = GA(25); g26 = GA(26); g27 = GA(27); }
      if (m > 28) { g28 = GA(28); g29 = GA(29); g30 = GA(30); g31 = GA(31); }
      #undef GA
      // ---- weights (overlap with gather latency) ----
      float wA = 0.f;
      if (lane < m) wA = __expf(lrelu(hs[sA] + hdi));
      if (lane < 32) wsh[wid][lane] = wA;    // full 32 slots (0-padded)
      float ws = wA;
      #pragma unroll
      for (int off = 32; off; off >>= 1) ws += __shfl_xor(ws, off);
      z += ws;
      // ---- consume ----
      #define CS(u, a) a = fmaf(wsh[wid][u], b2f(g##u), a)
      if (m > 0)  { CS(0, acc0);  CS(1, acc1);  CS(2, acc2);  CS(3, acc3);  }
      if (m > 4)  { CS(4, acc0);  CS(5, acc1);  CS(6, acc2);  CS(7, acc3);  }
      if (m > 8)  { CS(8, acc0);  CS(9, acc1);  CS(10, acc2); CS(11, acc3); }
      if (m > 12) { CS(12, acc0); CS(13, acc1); CS(14, acc2); CS(15, acc3); }
      if (m > 16) { CS(16, acc0); CS(17, acc1); CS(18, acc2); CS(19, acc3); }
      if (m > 20) { CS(20, acc0); CS(21, acc1); CS(22, acc2); CS(23, acc3); }
      if (m > 24) { CS(24, acc0); CS(25, acc1); CS(26, acc2); CS(27, acc3); }
      if (m > 28) { CS(28, acc0); CS(29, acc1); CS(30, acc2); CS(31, acc3); }
      #undef CS
    }
    val = ((acc0 + acc1) + (acc2 + acc3)) / z + bias[lane];
    y16[(size_t)node * 64 + lane] = f2b(val);
  }
  float s1r = val, s2r = val * val;
  #pragma unroll
  for (int off = 32; off; off >>= 1) { s1r += __shfl_xor(s1r, off); s2r += __shfl_xor(s2r, off); }
  if (lane == 0) { sh1[wid] = s1r; sh2[wid] = s2r; }
  __syncthreads();
  if (tid == 0) {
    part[(size_t)bb * 2 + 0] = sh1[0] + sh1[1] + sh1[2] + sh1[3];
    part[(size_t)bb * 2 + 1] = sh2[0] + sh2[1] + sh2[2] + sh2[3];
  }
}

// ---------------- LayerNorm stats reduce (both paths): part -> (mu, rstd) -------
__global__ __launch_bounds__(1024) void k_ln_stats(
    const float* __restrict__ part0, const float* __restrict__ part1,
    int nblk, float invCount,
    float* __restrict__ s0, float* __restrict__ s1)
{
  __shared__ float sh1[16], sh2[16];
  const float* part = blockIdx.x ? part1 : part0;
  float* so = blockIdx.x ? s1 : s0;
  float a = 0.f, b = 0.f;
  for (int i = threadIdx.x; i < nblk; i += 1024) { a += part[(size_t)i * 2]; b += part[(size_t)i * 2 + 1]; }
  #pragma unroll
  for (int off = 32; off; off >>= 1) { a += __shfl_xor(a, off); b += __shfl_xor(b, off); }
  const int wid = threadIdx.x >> 6, lane = threadIdx.x & 63;
  if (lane == 0) { sh1[wid] = a; sh2[wid] = b; }
  __syncthreads();
  if (threadIdx.x == 0) {
    float t1 = 0.f, t2 = 0.f;
    #pragma unroll
    for (int i = 0; i < 16; ++i) { t1 += sh1[i]; t2 += sh2[i]; }
    const float mu = t1 * invCount;
    so[0] = mu;
    so[1] = rsqrtf(t2 * invCount - mu * mu + LN_EPS);
  }
}

// ---------------- MLP head (MFMA): out = prelu(LN(y) @ W1 + b1) @ W2 + b2 -------
__global__ __launch_bounds__(256) void k_mlp(
    const ushort_t* __restrict__ y16, int N,
    const float* __restrict__ stats, const float* __restrict__ g,
    const float* __restrict__ be, const float* __restrict__ pe,
    const float* __restrict__ W1, const float* __restrict__ b1, const float* __restrict__ pm,
    const float* __restrict__ W2, const float* __restrict__ b2,
    float* __restrict__ outp)
{
  __shared__ ushort_t W1t[128 * 72];   // W1^T bf16 [f=128][k=64],  pitch 72
  __shared__ ushort_t W2t[64 * 136];   // W2^T bf16 [f=64][k=128],  pitch 136
  __shared__ ushort_t At[64 * 72];     // LN(y) tile bf16
  __shared__ ushort_t Tt[64 * 136];    // hidden tile bf16
  __shared__ float    Ob[64 * 68];     // out tile f32
  const int tid = threadIdx.x, wid = tid >> 6, lane = tid & 63;
  const int l15 = lane & 15, lhi = lane >> 4;

  for (int idx = tid; idx < 64 * 128; idx += 256) {   // W1 [64][128]
    const int k = idx >> 7, f = idx & 127;
    W1t[f * 72 + k] = f2b(W1[idx]);
  }
  for (int idx = tid; idx < 128 * 64; idx += 256) {   // W2 [128][64]
    const int k = idx >> 6, f = idx & 63;
    W2t[f * 136 + k] = f2b(W2[idx]);
  }
  __syncthreads();

  const float mu = stats[0], rstd = stats[1];
  const float p0 = pe[0], pm0 = pm[0];
  float b1f[8], b2f_[4];
  #pragma unroll
  for (int nt = 0; nt < 8; ++nt) b1f[nt] = b1[nt * 16 + l15];
  #pragma unroll
  for (int nt = 0; nt < 4; ++nt) b2f_[nt] = b2[nt * 16 + l15];

  const int nb = blockIdx.x << 6;
  {   // stage LN(y)+prelu tile from bf16 y
    const int r = tid >> 2;
    const int node = nb + r;
    if (node < N) {
      const int q = tid & 3;
      const int4* srcp = (const int4*)(y16 + (size_t)node * 64 + q * 16);
      const int4 A0 = srcp[0], A1 = srcp[1];
      const ushort_t* pu0 = (const ushort_t*)&A0;
      const ushort_t* pu1 = (const ushort_t*)&A1;
      float vv[16];
      #pragma unroll
      for (int i = 0; i < 8; ++i) { vv[i] = b2f(pu0[i]); vv[8 + i] = b2f(pu1[i]); }
      #pragma unroll
      for (int i2 = 0; i2 < 4; ++i2) {
        const int c4 = q * 4 + i2;
        const float4 gg = ((const float4*)g)[c4];
        const float4 bb = ((const float4*)be)[c4];
        float4 v;
        v.x = (vv[i2 * 4 + 0] - mu) * rstd * gg.x + bb.x;  v.x = v.x >= 0.f ? v.x : p0 * v.x;
        v.y = (vv[i2 * 4 + 1] - mu) * rstd * gg.y + bb.y;  v.y = v.y >= 0.f ? v.y : p0 * v.y;
        v.z = (vv[i2 * 4 + 2] - mu) * rstd * gg.z + bb.z;  v.z = v.z >= 0.f ? v.z : p0 * v.z;
        v.w = (vv[i2 * 4 + 3] - mu) * rstd * gg.w + bb.w;  v.w = v.w >= 0.f ? v.w : p0 * v.w;
        *(uint2*)&At[r * 72 + c4 * 4] = pack4(v);
      }
    }
  }
  __syncthreads();

  const f32x4 fz = {0.f, 0.f, 0.f, 0.f};
  f32x4 acc1[8];
  #pragma unroll
  for (int nt = 0; nt < 8; ++nt) acc1[nt] = fz;
  #pragma unroll
  for (int kt = 0; kt < 2; ++kt) {
    const bf16x8 Af = *(const bf16x8*)&At[(wid * 16 + l15) * 72 + kt * 32 + lhi * 8];
    #pragma unroll
    for (int nt = 0; nt < 8; ++nt) {
      const bf16x8 Bf = *(const bf16x8*)&W1t[(nt * 16 + l15) * 72 + kt * 32 + lhi * 8];
      acc1[nt] = __builtin_amdgcn_mfma_f32_16x16x32_bf16(Af, Bf, acc1[nt], 0, 0, 0);
    }
  }
  #pragma unroll
  for (int nt = 0; nt < 8; ++nt)
    #pragma unroll
    for (int r = 0; r < 4; ++r) {
      float v = acc1[nt][r] + b1f[nt];
      v = v >= 0.f ? v : pm0 * v;
      Tt[(wid * 16 + lhi * 4 + r) * 136 + nt * 16 + l15] = f2b(v);
    }
  __syncthreads();

  f32x4 acc2[4];
  #pragma unroll
  for (int nt = 0; nt < 4; ++nt) acc2[nt] = fz;
  #pragma unroll
  for (int kt = 0; kt < 4; ++kt) {
    const bf16x8 Af = *(const bf16x8*)&Tt[(wid * 16 + l15) * 136 + kt * 32 + lhi * 8];
    #pragma unroll
    for (int nt = 0; nt < 4; ++nt) {
      const bf16x8 Bf = *(const bf16x8*)&W2t[(nt * 16 + l15) * 136 + kt * 32 + lhi * 8];
      acc2[nt] = __builtin_amdgcn_mfma_f32_16x16x32_bf16(Af, Bf, acc2[nt], 0, 0, 0);
    }
  }
  #pragma unroll
  for (int nt = 0; nt < 4; ++nt)
    #pragma unroll
    for (int r = 0; r < 4; ++r)
      Ob[(wid * 16 + lhi * 4 + r) * 68 + nt * 16 + l15] = acc2[nt][r] + b2f_[nt];
  __syncthreads();
  {
    const int r = tid >> 2, chunk = tid & 3;
    const int node = nb + r;
    if (node < N) {
      const float4* sp = (const float4*)&Ob[r * 68 + chunk * 16];
      const float4 v0 = sp[0], v1 = sp[1], v2 = sp[2], v3 = sp[3];
      float4* dp = (float4*)(outp + (size_t)node * 64 + chunk * 16);
      dp[0] = v0; dp[1] = v1; dp[2] = v2; dp[3] = v3;
    }
  }
}

// ---------------- K-encoder final LN+PReLU (bf16 y -> f32 out) ------------------
__global__ void k_ln_prelu_out(const ushort_t* __restrict__ y16, int total8,
                               const float* __restrict__ stats,
                               const float* __restrict__ g,
                               const float* __restrict__ be, const float* __restrict__ pe,
                               float* __restrict__ o)
{
  const float mu = stats[0], rstd = stats[1];
  const float p0 = pe[0];
  int i = blockIdx.x * blockDim.x + threadIdx.x;
  const int stride = gridDim.x * blockDim.x;
  for (; i < total8; i += stride) {
    const int4 A = *(const int4*)(y16 + (size_t)i * 8);
    const ushort_t* pu = (const ushort_t*)&A;
    const int grp = i & 7;
    const float4 g0 = ((const float4*)g)[grp * 2], g1 = ((const float4*)g)[grp * 2 + 1];
    const float4 b0 = ((const float4*)be)[grp * 2], b1 = ((const float4*)be)[grp * 2 + 1];
    float4 o0, o1;
    o0.x = (b2f(pu[0]) - mu) * rstd * g0.x + b0.x;  o0.x = o0.x >= 0.f ? o0.x : p0 * o0.x;
    o0.y = (b2f(pu[1]) - mu) * rstd * g0.y + b0.y;  o0.y = o0.y >= 0.f ? o0.y : p0 * o0.y;
    o0.z = (b2f(pu[2]) - mu) * rstd * g0.z + b0.z;  o0.z = o0.z >= 0.f ? o0.z : p0 * o0.z;
    o0.w = (b2f(pu[3]) - mu) * rstd * g0.w + b0.w;  o0.w = o0.w >= 0.f ? o0.w : p0 * o0.w;
    o1.x = (b2f(pu[4]) - mu) * rstd * g1.x + b1.x;  o1.x = o1.x >= 0.f ? o1.x : p0 * o1.x;
    o1.y = (b2f(pu[5]) - mu) * rstd * g1.y + b1.y;  o1.y = o1.y >= 0.f ? o1.y : p0 * o1.y;
    o1.z = (b2f(pu[6]) - mu) * rstd * g1.z + b1.z;  o1.z = o1.z >= 0.f ? o1.z : p0 * o1.z;
    o1.w = (b2f(pu[7]) - mu) * rstd * g1.w + b1.w;  o1.w = o1.w >= 0.f ? o1.w : p0 * o1.w;
    float4* dp = (float4*)(o + (size_t)i * 8);
    dp[0] = o0; dp[1] = o1;
  }
}

// ================================================================================
extern "C" void kernel_launch(void* const* d_in, const int* in_sizes, int n_in,
                              void* d_out, int out_size, void* d_ws, size_t ws_size,
                              hipStream_t stream) {
  (void)n_in; (void)out_size; (void)ws_size;
  const int FIN = 128, F = 64;
  const int N = in_sizes[0] / FIN;
  const int E = in_sizes[2] / 2;

  const float* x_q = (const float*)d_in[0];
  const float* x_k = (const float*)d_in[1];
  const int*   ei_q = (const int*)d_in[2];
  const int*   ei_k = (const int*)d_in[3];
  const float* L[4][7];
  for (int l = 0; l < 4; ++l)
    for (int j = 0; j < 7; ++j) L[l][j] = (const float*)d_in[4 + l * 7 + j];
  const float* mW1 = (const float*)d_in[32];
  const float* mb1 = (const float*)d_in[33];
  const float* mp  = (const float*)d_in[34];
  const float* mW2 = (const float*)d_in[35];
  const float* mb2 = (const float*)d_in[36];
  float* out = (float*)d_out;

  const int CAP = (((E + NBUK - 1) / NBUK) * 5 / 4 + 3) & ~3;   // 1.25x mean (~19 sigma)

  char* w = (char*)d_ws;
  auto alloc = [&](size_t bytes) { char* r = w; w += (bytes + 255) & ~size_t(255); return r; };
  // big contiguous block: h16 x2, y16 x2 — pairs x2 alias it (free during CSR build)
  ushort_t* h16_0 = (ushort_t*)alloc((size_t)N * F * sizeof(ushort_t));
  ushort_t* h16_1 = (ushort_t*)alloc((size_t)N * F * sizeof(ushort_t));
  ushort_t* y16_0 = (ushort_t*)alloc((size_t)N * F * sizeof(ushort_t));
  ushort_t* y16_1 = (ushort_t*)alloc((size_t)N * F * sizeof(ushort_t));
  int2* pairs0 = (int2*)h16_0;                      // 2*NBUK*CAP*8B <= 4*N*F*2B
  int2* pairs1 = pairs0 + (size_t)NBUK * CAP;
  float* hs0 = (float*)alloc((size_t)N * sizeof(float));
  float* hs1 = (float*)alloc((size_t)N * sizeof(float));
  float* hd0 = (float*)alloc((size_t)N * sizeof(float));
  float* hd1 = (float*)alloc((size_t)N * sizeof(float));
  const int nblk = (N + 3) / 4;
  float* part0 = (float*)alloc((size_t)nblk * 2 * sizeof(float));
  float* part1 = (float*)alloc((size_t)nblk * 2 * sizeof(float));
  float* stats = (float*)alloc(16 * sizeof(float));   // {Q1,Q2,K1,K2} x (mu, rstd)
  int* rs0 = (int*)alloc((size_t)N * sizeof(int));
  int* rs1 = (int*)alloc((size_t)N * sizeof(int));
  int* re0 = (int*)alloc((size_t)N * sizeof(int));
  int* re1 = (int*)alloc((size_t)N * sizeof(int));
  int* csr0 = (int*)alloc((size_t)NBUK * CAP * sizeof(int));
  int* csr1 = (int*)alloc((size_t)NBUK * CAP * sizeof(int));
  int* bcur0 = (int*)alloc(NBUK * sizeof(int));
  int* bcur1 = (int*)alloc(NBUK * sizeof(int));

  const float invCount = 1.f / ((float)N * (float)F);
  const uint32_t bmul = (uint32_t)(((uint64_t)NBUK << 32) / (uint64_t)N);
  const int ntiles = (N + 63) / 64;
  const int nchunkE = (E + 4095) >> 12;

  // ---- CSR build, both graphs fused ----
  kb_init<<<1, NBUK, 0, stream>>>(bcur0, bcur1, CAP);
  kb_expand<<<2 * nchunkE, 256, 0, stream>>>(ei_q, ei_k, E, nchunkE,
                                             bcur0, bcur1, pairs0, pairs1, bmul);
  kb_sort<<<2 * NBUK, 256, 0, stream>>>(pairs0, pairs1, bcur0, bcur1,
                                        rs0, rs1, re0, re1, csr0, csr1, bmul, CAP, N);

  // ---- layer 1 (Q: q1, K: k1) ----
  k_gemm_att<128, false><<<2 * ntiles, 256, 0, stream>>>(
      x_q, x_k, N, ntiles,
      L[0][0], L[2][0], L[0][1], L[2][1], L[0][2], L[2][2],
      nullptr, nullptr, nullptr, nullptr, nullptr, nullptr, nullptr, nullptr,
      h16_0, h16_1, hs0, hs1, hd0, hd1);
  k_aggregate<<<2 * nblk, 256, 0, stream>>>(
      rs0, rs1, re0, re1, csr0, csr1, h16_0, h16_1, hs0, hs1, hd0, hd1,
      L[0][3], L[2][3], N, nblk, y16_0, y16_1, part0, part1);
  k_ln_stats<<<2, 1024, 0, stream>>>(part0, part1, nblk, invCount, stats + 0, stats + 4);

  // ---- layer 2 (Q: q2 with q1 LN params, K: k2 with k1 LN params) ----
  k_gemm_att<64, true><<<2 * ntiles, 256, 0, stream>>>(
      y16_0, y16_1, N, ntiles,
      L[1][0], L[3][0], L[1][1], L[3][1], L[1][2], L[3][2],
      stats + 0, stats + 4, L[0][4], L[2][4], L[0][5], L[2][5], L[0][6], L[2][6],
      h16_0, h16_1, hs0, hs1, hd0, hd1);
  k_aggregate<<<2 * nblk, 256, 0, stream>>>(
      rs0, rs1, re0, re1, csr0, csr1, h16_0, h16_1, hs0, hs1, hd0, hd1,
      L[1][3], L[3][3], N, nblk, y16_0, y16_1, part0, part1);
  k_ln_stats<<<2, 1024, 0, stream>>>(part0, part1, nblk, invCount, stats + 2, stats + 6);

  // ---- epilogues ----
  k_mlp<<<ntiles, 256, 0, stream>>>(y16_0, N, stats + 2, L[1][4], L[1][5], L[1][6],
                                    mW1, mb1, mp, mW2, mb2, out);
  const int total8 = N * F / 8;
  k_ln_prelu_out<<<2048, 256, 0, stream>>>(y16_1, total8, stats + 6,
                                           L[3][4], L[3][5], L[3][6],
                                           out + (size_t)N * F);
}

// Round 14
// 398.698 us; speedup vs baseline: 6.9287x; 1.0006x over previous
//
#include <hip/hip_runtime.h>
#include <cstddef>
#include <cstdint>

#define NEG_SLOPE 0.2f
#define LN_EPS    1e-5f
#define NBUK      256      // buckets for CSR counting sort
#define MAXNPB    512      // max nodes per bucket (LDS histogram size)

typedef unsigned short ushort_t;
typedef short bf16x8 __attribute__((ext_vector_type(8)));
typedef float f32x4  __attribute__((ext_vector_type(4)));

__device__ __forceinline__ float lrelu(float s) { return s >= 0.f ? s : NEG_SLOPE * s; }
__device__ __forceinline__ float b2f(ushort_t u) { return __uint_as_float(((uint32_t)u) << 16); }
__device__ __forceinline__ ushort_t f2b(float f) {   // round-to-nearest-even (finite inputs)
  uint32_t u = __float_as_uint(f);
  return (ushort_t)((u + 0x7fffu + ((u >> 16) & 1u)) >> 16);
}
__device__ __forceinline__ uint2 pack4(float4 v) {
  uint2 r;
  r.x = (uint32_t)f2b(v.x) | ((uint32_t)f2b(v.y) << 16);
  r.y = (uint32_t)f2b(v.z) | ((uint32_t)f2b(v.w) << 16);
  return r;
}

// ============== CSR build: single-pass bucketed counting sort, Q||K fused ==========
// pairs record packed to u32: (src << 9) | (dst - n0(bucket)); src < 2^23,
// nodes-per-bucket < 512. Halves the pairs round-trip vs int2.
__global__ void kb_init(int* __restrict__ b0, int* __restrict__ b1, int cap) {
  b0[threadIdx.x] = threadIdx.x * cap;
  b1[threadIdx.x] = threadIdx.x * cap;
}

__global__ __launch_bounds__(256) void kb_expand(
    const int* __restrict__ ei0, const int* __restrict__ ei1, int E, int nchunk,
    int* __restrict__ bcur0, int* __restrict__ bcur1,
    uint32_t* __restrict__ pairs0, uint32_t* __restrict__ pairs1,
    uint32_t bmul, int N) {
  __shared__ int hist[NBUK], base[NBUK], lcnt[NBUK], n0tab[NBUK];
  const int tid = threadIdx.x;
  const int path = (blockIdx.x >= (unsigned)nchunk) ? 1 : 0;
  const int c = blockIdx.x - path * nchunk;
  const int* src = path ? ei1 : ei0;
  const int* dst = src + E;
  int* gbcur = path ? bcur1 : bcur0;
  uint32_t* pairs = path ? pairs1 : pairs0;

  {
    const int nl = (int)((((uint64_t)tid << 32) + bmul - 1) / bmul);
    n0tab[tid] = nl < N ? nl : N;
  }
  const int e0 = c << 12;
  hist[tid] = 0; lcnt[tid] = 0;
  __syncthreads();
  int sv[16], dv[16], bv[16];
  #pragma unroll
  for (int u = 0; u < 16; ++u) {
    const int i = e0 + u * 256 + tid;
    if (i < E) {
      sv[u] = src[i]; dv[u] = dst[i];
      bv[u] = (int)__umulhi((uint32_t)dv[u], bmul);
      atomicAdd(&hist[bv[u]], 1);
    } else bv[u] = -1;
  }
  __syncthreads();
  base[tid] = atomicAdd(&gbcur[tid], hist[tid]);
  __syncthreads();
  #pragma unroll
  for (int u = 0; u < 16; ++u) {
    if (bv[u] >= 0) {
      const int pos = atomicAdd(&lcnt[bv[u]], 1);
      pairs[base[bv[u]] + pos] =
          ((uint32_t)sv[u] << 9) | (uint32_t)(dv[u] - n0tab[bv[u]]);
    }
  }
}

__global__ __launch_bounds__(256) void kb_sort(
    const uint32_t* __restrict__ pairs0, const uint32_t* __restrict__ pairs1,
    const int* __restrict__ bcur0, const int* __restrict__ bcur1,
    int* __restrict__ rs0, int* __restrict__ rs1,
    int* __restrict__ re0, int* __restrict__ re1,
    int* __restrict__ csr0, int* __restrict__ csr1,
    uint32_t bmul, int cap, int N) {
  __shared__ int hist[MAXNPB];
  __shared__ int ps[256];
  const int path = (blockIdx.x >= NBUK) ? 1 : 0;
  const int b = blockIdx.x & (NBUK - 1);
  const int tid = threadIdx.x;
  const uint32_t* pairs = path ? pairs1 : pairs0;
  const int* gbcur = path ? bcur1 : bcur0;
  int* rs = path ? rs1 : rs0;
  int* re = path ? re1 : re0;
  int* csr = path ? csr1 : csr0;

  int n0 = (int)((((uint64_t)b << 32) + bmul - 1) / bmul);
  int n1 = (int)((((uint64_t)(b + 1) << 32) + bmul - 1) / bmul);
  n0 = n0 < N ? n0 : N;
  n1 = n1 < N ? n1 : N;
  const int nn = n1 - n0;
  const int e0 = b * cap;
  const int e1 = min(gbcur[b], e0 + cap);
  for (int k = tid; k < nn; k += 256) hist[k] = 0;
  __syncthreads();
  for (int i = e0 + tid; i < e1; i += 256) atomicAdd(&hist[pairs[i] & 511u], 1);
  __syncthreads();
  const int i0 = 2 * tid, i1 = 2 * tid + 1;
  const int a = (i0 < nn) ? hist[i0] : 0;
  const int c = (i1 < nn) ? hist[i1] : 0;
  const int tot = a + c;
  ps[tid] = tot;
  __syncthreads();
  for (int off = 1; off < 256; off <<= 1) {
    const int x = (tid >= off) ? ps[tid - off] : 0;
    __syncthreads();
    ps[tid] += x;
    __syncthreads();
  }
  const int excl = ps[tid] - tot;
  if (i0 < nn) { hist[i0] = excl;     rs[n0 + i0] = e0 + excl;     re[n0 + i0] = e0 + excl + a; }
  if (i1 < nn) { hist[i1] = excl + a; rs[n0 + i1] = e0 + excl + a; re[n0 + i1] = e0 + excl + a + c; }
  __syncthreads();
  for (int i = e0 + tid; i < e1; i += 256) {
    const uint32_t v = pairs[i];
    const int p = atomicAdd(&hist[v & 511u], 1);
    csr[e0 + p] = (int)(v >> 9);
  }
}

// ---------------- MFMA GEMM (h = act @ W) + attention dots, Q||K fused ----------
// act f32 for layer 1 (LNF=false), bf16 for layer 2 (LNF=true; stats = {mu,rstd}).
template <int FI, bool LNF>
__global__ __launch_bounds__(256) void k_gemm_att(
    const void* __restrict__ act0, const void* __restrict__ act1, int N, int ntiles,
    const float* __restrict__ W0, const float* __restrict__ W1x,
    const float* __restrict__ as0, const float* __restrict__ as1,
    const float* __restrict__ ad0, const float* __restrict__ ad1,
    const float* __restrict__ st0, const float* __restrict__ st1,
    const float* __restrict__ g0, const float* __restrict__ g1,
    const float* __restrict__ be0, const float* __restrict__ be1,
    const float* __restrict__ pp0, const float* __restrict__ pp1,
    ushort_t* __restrict__ h0, ushort_t* __restrict__ h1,
    float* __restrict__ hs0, float* __restrict__ hs1,
    float* __restrict__ hd0, float* __restrict__ hd1)
{
  constexpr int P = FI + 8;                 // bf16 row pitch: +16B pad -> 4-bank rotation
  __shared__ ushort_t S[64 * P];            // Wt stage, then act tile / out tile
  const int tid = threadIdx.x, wid = tid >> 6, lane = tid & 63;
  const int l15 = lane & 15, lhi = lane >> 4;

  const int path = (blockIdx.x >= (unsigned)ntiles) ? 1 : 0;
  const int tile = blockIdx.x - path * ntiles;
  const void* act = path ? act1 : act0;
  const float* W  = path ? W1x : W0;
  const float* a_s = path ? as1 : as0;
  const float* a_d = path ? ad1 : ad0;
  const float* stats = path ? st1 : st0;
  const float* g  = path ? g1 : g0;
  const float* be = path ? be1 : be0;
  const float* pp = path ? pp1 : pp0;
  ushort_t* h16 = path ? h1 : h0;
  float* hs = path ? hs1 : hs0;
  float* hd = path ? hd1 : hd0;

  for (int idx = tid; idx < FI * 64; idx += 256) {
    const int k = idx >> 6, f = idx & 63;
    S[f * P + k] = f2b(W[idx]);
  }
  __syncthreads();
  bf16x8 Bf[FI / 32][4];
  #pragma unroll
  for (int kt = 0; kt < FI / 32; ++kt)
    #pragma unroll
    for (int nt = 0; nt < 4; ++nt)
      Bf[kt][nt] = *(const bf16x8*)&S[(nt * 16 + l15) * P + kt * 32 + lhi * 8];
  __syncthreads();

  float asf[4], adf[4];
  #pragma unroll
  for (int nt = 0; nt < 4; ++nt) { asf[nt] = a_s[nt * 16 + l15]; adf[nt] = a_d[nt * 16 + l15]; }
  float mu = 0.f, rstd = 1.f, p0 = 0.f;
  if (LNF) { mu = stats[0]; rstd = stats[1]; p0 = pp[0]; }

  const int nb = tile << 6;
  {   // stage activation tile -> bf16 LDS
    const int r = tid >> 2;
    const int node = nb + r;
    if (node < N) {
      if (LNF) {   // bf16 input (aggregated y), fuse LN+PReLU
        const ushort_t* a16 = (const ushort_t*)act;
        const int q = tid & 3;   // 16-feature chunk
        const int4* srcp = (const int4*)(a16 + (size_t)node * 64 + q * 16);
        const int4 A0 = srcp[0], A1 = srcp[1];
        const ushort_t* pu0 = (const ushort_t*)&A0;
        const ushort_t* pu1 = (const ushort_t*)&A1;
        float vv[16];
        #pragma unroll
        for (int i = 0; i < 8; ++i) { vv[i] = b2f(pu0[i]); vv[8 + i] = b2f(pu1[i]); }
        #pragma unroll
        for (int i2 = 0; i2 < 4; ++i2) {
          const int c4 = q * 4 + i2;
          const float4 gg = ((const float4*)g)[c4];
          const float4 bb = ((const float4*)be)[c4];
          float4 v;
          v.x = (vv[i2 * 4 + 0] - mu) * rstd * gg.x + bb.x;  v.x = v.x >= 0.f ? v.x : p0 * v.x;
          v.y = (vv[i2 * 4 + 1] - mu) * rstd * gg.y + bb.y;  v.y = v.y >= 0.f ? v.y : p0 * v.y;
          v.z = (vv[i2 * 4 + 2] - mu) * rstd * gg.z + bb.z;  v.z = v.z >= 0.f ? v.z : p0 * v.z;
          v.w = (vv[i2 * 4 + 3] - mu) * rstd * gg.w + bb.w;  v.w = v.w >= 0.f ? v.w : p0 * v.w;
          *(uint2*)&S[r * P + c4 * 4] = pack4(v);
        }
      } else {     // f32 input (x)
        const float4* srcp = (const float4*)((const float*)act + (size_t)node * FI);
        #pragma unroll
        for (int i = 0; i < FI / 16; ++i) {
          const int c = (tid & 3) * (FI / 4) + i * 4;
          const float4 v = srcp[c >> 2];
          *(uint2*)&S[r * P + c] = pack4(v);
        }
      }
    }
  }
  __syncthreads();

  const f32x4 fz = {0.f, 0.f, 0.f, 0.f};
  f32x4 acc[4]; acc[0] = fz; acc[1] = fz; acc[2] = fz; acc[3] = fz;
  #pragma unroll
  for (int kt = 0; kt < FI / 32; ++kt) {
    const bf16x8 Af = *(const bf16x8*)&S[(wid * 16 + l15) * P + kt * 32 + lhi * 8];
    #pragma unroll
    for (int nt = 0; nt < 4; ++nt)
      acc[nt] = __builtin_amdgcn_mfma_f32_16x16x32_bf16(Af, Bf[kt][nt], acc[nt], 0, 0, 0);
  }
  #pragma unroll
  for (int r = 0; r < 4; ++r) {
    float ps = acc[0][r] * asf[0] + acc[1][r] * asf[1] + acc[2][r] * asf[2] + acc[3][r] * asf[3];
    float pd = acc[0][r] * adf[0] + acc[1][r] * adf[1] + acc[2][r] * adf[2] + acc[3][r] * adf[3];
    #pragma unroll
    for (int off = 1; off < 16; off <<= 1) { ps += __shfl_xor(ps, off); pd += __shfl_xor(pd, off); }
    const int node = nb + wid * 16 + lhi * 4 + r;
    if (l15 == 0 && node < N) { hs[node] = ps; hd[node] = pd; }
  }
  #pragma unroll
  for (int nt = 0; nt < 4; ++nt)
    #pragma unroll
    for (int r = 0; r < 4; ++r)
      S[(wid * 16 + lhi * 4 + r) * P + nt * 16 + l15] = f2b(acc[nt][r]);
  __syncthreads();
  {
    const int r = tid >> 2, chunk = tid & 3;
    const int node = nb + r;
    if (node < N) {
      const int4* sp = (const int4*)&S[r * P + chunk * 16];
      const int4 v0 = sp[0], v1 = sp[1];
      int4* dp = (int4*)(h16 + (size_t)node * 64 + chunk * 16);
      dp[0] = v0; dp[1] = v1;
    }
  }
}

// ---------------- GAT aggregation, Q||K fused ----------------------------------
// Chunk = 32 edges, static issue/consume split (measured floor: ~22cyc/gather/CU,
// MSHR-limited; FETCH ~= 8 XCD x |h16| = structural minimum for random graphs).
__global__ __launch_bounds__(256) void k_aggregate(
    const int* __restrict__ rs0, const int* __restrict__ rs1,
    const int* __restrict__ re0, const int* __restrict__ re1,
    const int* __restrict__ csr0, const int* __restrict__ csr1,
    const ushort_t* __restrict__ h0, const ushort_t* __restrict__ h1,
    const float* __restrict__ hs0, const float* __restrict__ hs1,
    const float* __restrict__ hd0, const float* __restrict__ hd1,
    const float* __restrict__ bias0, const float* __restrict__ bias1,
    int N, int nblk,
    ushort_t* __restrict__ y0, ushort_t* __restrict__ y1,
    float* __restrict__ part0, float* __restrict__ part1)
{
  __shared__ float wsh[4][32];
  __shared__ float sh1[4], sh2[4];
  const int tid = threadIdx.x, wid = tid >> 6, lane = tid & 63;
  const int path = (blockIdx.x >= (unsigned)nblk) ? 1 : 0;
  const int bb = blockIdx.x - path * nblk;
  const int* rs = path ? rs1 : rs0;
  const int* re = path ? re1 : re0;
  const int* csr = path ? csr1 : csr0;
  const ushort_t* h16 = path ? h1 : h0;
  const float* hs = path ? hs1 : hs0;
  const float* hd = path ? hd1 : hd0;
  const float* bias = path ? bias1 : bias0;
  ushort_t* y16 = path ? y1 : y0;
  float* part = path ? part1 : part0;

  const int node = bb * 4 + wid;
  float val = 0.f;
  if (node < N) {
    const float hdi = hd[node];
    const float wself = __expf(lrelu(hs[node] + hdi));   // self loop
    float z = wself;
    float acc0 = wself * b2f(h16[((size_t)(uint32_t)node << 6) + lane]);
    float acc1 = 0.f, acc2 = 0.f, acc3 = 0.f;
    const int st = __builtin_amdgcn_readfirstlane(rs[node]);
    const int en = __builtin_amdgcn_readfirstlane(re[node]);
    for (int j = st; j < en; j += 32) {
      const int m = min(32, en - j);
      int sA = 0;
      if (lane < m) sA = csr[j + lane];
      // ---- issue gathers (4-granular) ----
      #define GA(u) h16[((size_t)(uint32_t)__builtin_amdgcn_readlane(sA, u) << 6) + lane]
      ushort_t g0 = 0, g1 = 0, g2 = 0, g3 = 0, g4 = 0, g5 = 0, g6 = 0, g7 = 0;
      ushort_t g8 = 0, g9 = 0, g10 = 0, g11 = 0, g12 = 0, g13 = 0, g14 = 0, g15 = 0;
      ushort_t g16 = 0, g17 = 0, g18 = 0, g19 = 0, g20 = 0, g21 = 0, g22 = 0, g23 = 0;
      ushort_t g24 = 0, g25 = 0, g26 = 0, g27 = 0, g28 = 0, g29 = 0, g30 = 0, g31 = 0;
      if (m > 0)  { g0  = GA(0);  g1  = GA(1);  g2  = GA(2);  g3  = GA(3);  }
      if (m > 4)  { g4  = GA(4);  g5  = GA(5);  g6  = GA(6);  g7  = GA(7);  }
      if (m > 8)  { g8  = GA(8);  g9  = GA(9);  g10 = GA(10); g11 = GA(11); }
      if (m > 12) { g12 = GA(12); g13 = GA(13); g14 = GA(14); g15 = GA(15); }
      if (m > 16) { g16 = GA(16); g17 = GA(17); g18 = GA(18); g19 = GA(19); }
      if (m > 20) { g20 = GA(20); g21 = GA(21); g22 = GA(22); g23 = GA(23); }
      if (m > 24) { g24 = GA(24); g25 = GA(25); g26 = GA(26); g27 = GA(27); }
      if (m > 28) { g28 = GA(28); g29 = GA(29); g30 = GA(30); g31 = GA(31); }
      #undef GA
      // ---- weights (overlap with gather latency) ----
      float wA = 0.f;
      if (lane < m) wA = __expf(lrelu(hs[sA] + hdi));
      if (lane < 32) wsh[wid][lane] = wA;    // full 32 slots (0-padded)
      float ws = wA;
      #pragma unroll
      for (int off = 32; off; off >>= 1) ws += __shfl_xor(ws, off);
      z += ws;
      // ---- consume ----
      #define CS(u, a) a = fmaf(wsh[wid][u], b2f(g##u), a)
      if (m > 0)  { CS(0, acc0);  CS(1, acc1);  CS(2, acc2);  CS(3, acc3);  }
      if (m > 4)  { CS(4, acc0);  CS(5, acc1);  CS(6, acc2);  CS(7, acc3);  }
      if (m > 8)  { CS(8, acc0);  CS(9, acc1);  CS(10, acc2); CS(11, acc3); }
      if (m > 12) { CS(12, acc0); CS(13, acc1); CS(14, acc2); CS(15, acc3); }
      if (m > 16) { CS(16, acc0); CS(17, acc1); CS(18, acc2); CS(19, acc3); }
      if (m > 20) { CS(20, acc0); CS(21, acc1); CS(22, acc2); CS(23, acc3); }
      if (m > 24) { CS(24, acc0); CS(25, acc1); CS(26, acc2); CS(27, acc3); }
      if (m > 28) { CS(28, acc0); CS(29, acc1); CS(30, acc2); CS(31, acc3); }
      #undef CS
    }
    val = ((acc0 + acc1) + (acc2 + acc3)) / z + bias[lane];
    y16[(size_t)node * 64 + lane] = f2b(val);
  }
  float s1r = val, s2r = val * val;
  #pragma unroll
  for (int off = 32; off; off >>= 1) { s1r += __shfl_xor(s1r, off); s2r += __shfl_xor(s2r, off); }
  if (lane == 0) { sh1[wid] = s1r; sh2[wid] = s2r; }
  __syncthreads();
  if (tid == 0) {
    part[(size_t)bb * 2 + 0] = sh1[0] + sh1[1] + sh1[2] + sh1[3];
    part[(size_t)bb * 2 + 1] = sh2[0] + sh2[1] + sh2[2] + sh2[3];
  }
}

// ---------------- LayerNorm stats reduce (both paths): part -> (mu, rstd) -------
__global__ __launch_bounds__(1024) void k_ln_stats(
    const float* __restrict__ part0, const float* __restrict__ part1,
    int nblk, float invCount,
    float* __restrict__ s0, float* __restrict__ s1)
{
  __shared__ float sh1[16], sh2[16];
  const float* part = blockIdx.x ? part1 : part0;
  float* so = blockIdx.x ? s1 : s0;
  float a = 0.f, b = 0.f;
  for (int i = threadIdx.x; i < nblk; i += 1024) { a += part[(size_t)i * 2]; b += part[(size_t)i * 2 + 1]; }
  #pragma unroll
  for (int off = 32; off; off >>= 1) { a += __shfl_xor(a, off); b += __shfl_xor(b, off); }
  const int wid = threadIdx.x >> 6, lane = threadIdx.x & 63;
  if (lane == 0) { sh1[wid] = a; sh2[wid] = b; }
  __syncthreads();
  if (threadIdx.x == 0) {
    float t1 = 0.f, t2 = 0.f;
    #pragma unroll
    for (int i = 0; i < 16; ++i) { t1 += sh1[i]; t2 += sh2[i]; }
    const float mu = t1 * invCount;
    so[0] = mu;
    so[1] = rsqrtf(t2 * invCount - mu * mu + LN_EPS);
  }
}

// ---------------- Fused epilogue ------------------------------------------------
// blocks [0, ntiles):          Q head  out[:N] = prelu(LN(yQ) @ W1 + b1) @ W2 + b2
// blocks [ntiles, ntiles+NLB): K tail  out[N:] = prelu(LN(yK))   (grid-stride)
#define NLB 1024
__global__ __launch_bounds__(256) void k_epilogue(
    const ushort_t* __restrict__ yQ, const ushort_t* __restrict__ yK, int N, int ntiles,
    const float* __restrict__ stQ, const float* __restrict__ stK,
    const float* __restrict__ gQ, const float* __restrict__ beQ, const float* __restrict__ peQ,
    const float* __restrict__ W1, const float* __restrict__ b1, const float* __restrict__ pm,
    const float* __restrict__ W2, const float* __restrict__ b2,
    const float* __restrict__ gK, const float* __restrict__ beK, const float* __restrict__ peK,
    float* __restrict__ outp)
{
  __shared__ ushort_t W1t[128 * 72];   // W1^T bf16 [f=128][k=64],  pitch 72
  __shared__ ushort_t W2t[64 * 136];   // W2^T bf16 [f=64][k=128],  pitch 136
  __shared__ ushort_t At[64 * 72];     // LN(y) tile bf16
  __shared__ ushort_t Tt[64 * 136];    // hidden tile bf16
  __shared__ float    Ob[64 * 68];     // out tile f32
  const int tid = threadIdx.x;

  if (blockIdx.x >= (unsigned)ntiles) {   // ---- K tail: LN+PReLU stream ----
    const float mu = stK[0], rstd = stK[1];
    const float p0 = peK[0];
    const int total8 = N * 8;             // N*64/8
    float* o = outp + (size_t)N * 64;
    int i = (blockIdx.x - ntiles) * 256 + tid;
    const int stride = NLB * 256;
    for (; i < total8; i += stride) {
      const int4 A = *(const int4*)(yK + (size_t)i * 8);
      const ushort_t* pu = (const ushort_t*)&A;
      const int grp = i & 7;
      const float4 g0 = ((const float4*)gK)[grp * 2], g1 = ((const float4*)gK)[grp * 2 + 1];
      const float4 b0 = ((const float4*)beK)[grp * 2], b1v = ((const float4*)beK)[grp * 2 + 1];
      float4 o0, o1;
      o0.x = (b2f(pu[0]) - mu) * rstd * g0.x + b0.x;  o0.x = o0.x >= 0.f ? o0.x : p0 * o0.x;
      o0.y = (b2f(pu[1]) - mu) * rstd * g0.y + b0.y;  o0.y = o0.y >= 0.f ? o0.y : p0 * o0.y;
      o0.z = (b2f(pu[2]) - mu) * rstd * g0.z + b0.z;  o0.z = o0.z >= 0.f ? o0.z : p0 * o0.z;
      o0.w = (b2f(pu[3]) - mu) * rstd * g0.w + b0.w;  o0.w = o0.w >= 0.f ? o0.w : p0 * o0.w;
      o1.x = (b2f(pu[4]) - mu) * rstd * g1.x + b1v.x;  o1.x = o1.x >= 0.f ? o1.x : p0 * o1.x;
      o1.y = (b2f(pu[5]) - mu) * rstd * g1.y + b1v.y;  o1.y = o1.y >= 0.f ? o1.y : p0 * o1.y;
      o1.z = (b2f(pu[6]) - mu) * rstd * g1.z + b1v.z;  o1.z = o1.z >= 0.f ? o1.z : p0 * o1.z;
      o1.w = (b2f(pu[7]) - mu) * rstd * g1.w + b1v.w;  o1.w = o1.w >= 0.f ? o1.w : p0 * o1.w;
      float4* dp = (float4*)(o + (size_t)i * 8);
      dp[0] = o0; dp[1] = o1;
    }
    return;
  }

  // ---- Q head: MLP (MFMA) ----
  const int wid = tid >> 6, lane = tid & 63;
  const int l15 = lane & 15, lhi = lane >> 4;

  for (int idx = tid; idx < 64 * 128; idx += 256) {   // W1 [64][128]
    const int k = idx >> 7, f = idx & 127;
    W1t[f * 72 + k] = f2b(W1[idx]);
  }
  for (int idx = tid; idx < 128 * 64; idx += 256) {   // W2 [128][64]
    const int k = idx >> 6, f = idx & 63;
    W2t[f * 136 + k] = f2b(W2[idx]);
  }
  __syncthreads();

  const float mu = stQ[0], rstd = stQ[1];
  const float p0 = peQ[0], pm0 = pm[0];
  float b1f[8], b2f_[4];
  #pragma unroll
  for (int nt = 0; nt < 8; ++nt) b1f[nt] = b1[nt * 16 + l15];
  #pragma unroll
  for (int nt = 0; nt < 4; ++nt) b2f_[nt] = b2[nt * 16 + l15];

  const int nb = blockIdx.x << 6;
  {   // stage LN(y)+prelu tile from bf16 y
    const int r = tid >> 2;
    const int node = nb + r;
    if (node < N) {
      const int q = tid & 3;
      const int4* srcp = (const int4*)(yQ + (size_t)node * 64 + q * 16);
      const int4 A0 = srcp[0], A1 = srcp[1];
      const ushort_t* pu0 = (const ushort_t*)&A0;
      const ushort_t* pu1 = (const ushort_t*)&A1;
      float vv[16];
      #pragma unroll
      for (int i = 0; i < 8; ++i) { vv[i] = b2f(pu0[i]); vv[8 + i] = b2f(pu1[i]); }
      #pragma unroll
      for (int i2 = 0; i2 < 4; ++i2) {
        const int c4 = q * 4 + i2;
        const float4 gg = ((const float4*)gQ)[c4];
        const float4 bb = ((const float4*)beQ)[c4];
        float4 v;
        v.x = (vv[i2 * 4 + 0] - mu) * rstd * gg.x + bb.x;  v.x = v.x >= 0.f ? v.x : p0 * v.x;
        v.y = (vv[i2 * 4 + 1] - mu) * rstd * gg.y + bb.y;  v.y = v.y >= 0.f ? v.y : p0 * v.y;
        v.z = (vv[i2 * 4 + 2] - mu) * rstd * gg.z + bb.z;  v.z = v.z >= 0.f ? v.z : p0 * v.z;
        v.w = (vv[i2 * 4 + 3] - mu) * rstd * gg.w + bb.w;  v.w = v.w >= 0.f ? v.w : p0 * v.w;
        *(uint2*)&At[r * 72 + c4 * 4] = pack4(v);
      }
    }
  }
  __syncthreads();

  const f32x4 fz = {0.f, 0.f, 0.f, 0.f};
  f32x4 acc1[8];
  #pragma unroll
  for (int nt = 0; nt < 8; ++nt) acc1[nt] = fz;
  #pragma unroll
  for (int kt = 0; kt < 2; ++kt) {
    const bf16x8 Af = *(const bf16x8*)&At[(wid * 16 + l15) * 72 + kt * 32 + lhi * 8];
    #pragma unroll
    for (int nt = 0; nt < 8; ++nt) {
      const bf16x8 Bf = *(const bf16x8*)&W1t[(nt * 16 + l15) * 72 + kt * 32 + lhi * 8];
      acc1[nt] = __builtin_amdgcn_mfma_f32_16x16x32_bf16(Af, Bf, acc1[nt], 0, 0, 0);
    }
  }
  #pragma unroll
  for (int nt = 0; nt < 8; ++nt)
    #pragma unroll
    for (int r = 0; r < 4; ++r) {
      float v = acc1[nt][r] + b1f[nt];
      v = v >= 0.f ? v : pm0 * v;
      Tt[(wid * 16 + lhi * 4 + r) * 136 + nt * 16 + l15] = f2b(v);
    }
  __syncthreads();

  f32x4 acc2[4];
  #pragma unroll
  for (int nt = 0; nt < 4; ++nt) acc2[nt] = fz;
  #pragma unroll
  for (int kt = 0; kt < 4; ++kt) {
    const bf16x8 Af = *(const bf16x8*)&Tt[(wid * 16 + l15) * 136 + kt * 32 + lhi * 8];
    #pragma unroll
    for (int nt = 0; nt < 4; ++nt) {
      const bf16x8 Bf = *(const bf16x8*)&W2t[(nt * 16 + l15) * 136 + kt * 32 + lhi * 8];
      acc2[nt] = __builtin_amdgcn_mfma_f32_16x16x32_bf16(Af, Bf, acc2[nt], 0, 0, 0);
    }
  }
  #pragma unroll
  for (int nt = 0; nt < 4; ++nt)
    #pragma unroll
    for (int r = 0; r < 4; ++r)
      Ob[(wid * 16 + lhi * 4 + r) * 68 + nt * 16 + l15] = acc2[nt][r] + b2f_[nt];
  __syncthreads();
  {
    const int r = tid >> 2, chunk = tid & 3;
    const int node = nb + r;
    if (node < N) {
      const float4* sp = (const float4*)&Ob[r * 68 + chunk * 16];
      const float4 v0 = sp[0], v1 = sp[1], v2 = sp[2], v3 = sp[3];
      float4* dp = (float4*)(outp + (size_t)node * 64 + chunk * 16);
      dp[0] = v0; dp[1] = v1; dp[2] = v2; dp[3] = v3;
    }
  }
}

// ================================================================================
extern "C" void kernel_launch(void* const* d_in, const int* in_sizes, int n_in,
                              void* d_out, int out_size, void* d_ws, size_t ws_size,
                              hipStream_t stream) {
  (void)n_in; (void)out_size; (void)ws_size;
  const int FIN = 128, F = 64;
  const int N = in_sizes[0] / FIN;
  const int E = in_sizes[2] / 2;

  const float* x_q = (const float*)d_in[0];
  const float* x_k = (const float*)d_in[1];
  const int*   ei_q = (const int*)d_in[2];
  const int*   ei_k = (const int*)d_in[3];
  const float* L[4][7];
  for (int l = 0; l < 4; ++l)
    for (int j = 0; j < 7; ++j) L[l][j] = (const float*)d_in[4 + l * 7 + j];
  const float* mW1 = (const float*)d_in[32];
  const float* mb1 = (const float*)d_in[33];
  const float* mp  = (const float*)d_in[34];
  const float* mW2 = (const float*)d_in[35];
  const float* mb2 = (const float*)d_in[36];
  float* out = (float*)d_out;

  const int CAP = (((E + NBUK - 1) / NBUK) * 5 / 4 + 3) & ~3;   // 1.25x mean (~19 sigma)

  char* w = (char*)d_ws;
  auto alloc = [&](size_t bytes) { char* r = w; w += (bytes + 255) & ~size_t(255); return r; };
  // big contiguous block: h16 x2, y16 x2 — pairs x2 alias it (free during CSR build)
  ushort_t* h16_0 = (ushort_t*)alloc((size_t)N * F * sizeof(ushort_t));
  ushort_t* h16_1 = (ushort_t*)alloc((size_t)N * F * sizeof(ushort_t));
  ushort_t* y16_0 = (ushort_t*)alloc((size_t)N * F * sizeof(ushort_t));
  ushort_t* y16_1 = (ushort_t*)alloc((size_t)N * F * sizeof(ushort_t));
  uint32_t* pairs0 = (uint32_t*)h16_0;              // 2*NBUK*CAP*4B <= 4*N*F*2B
  uint32_t* pairs1 = pairs0 + (size_t)NBUK * CAP;
  float* hs0 = (float*)alloc((size_t)N * sizeof(float));
  float* hs1 = (float*)alloc((size_t)N * sizeof(float));
  float* hd0 = (float*)alloc((size_t)N * sizeof(float));
  float* hd1 = (float*)alloc((size_t)N * sizeof(float));
  const int nblk = (N + 3) / 4;
  float* part0 = (float*)alloc((size_t)nblk * 2 * sizeof(float));
  float* part1 = (float*)alloc((size_t)nblk * 2 * sizeof(float));
  float* stats = (float*)alloc(16 * sizeof(float));   // {Q1,Q2,K1,K2} x (mu, rstd)
  int* rs0 = (int*)alloc((size_t)N * sizeof(int));
  int* rs1 = (int*)alloc((size_t)N * sizeof(int));
  int* re0 = (int*)alloc((size_t)N * sizeof(int));
  int* re1 = (int*)alloc((size_t)N * sizeof(int));
  int* csr0 = (int*)alloc((size_t)NBUK * CAP * sizeof(int));
  int* csr1 = (int*)alloc((size_t)NBUK * CAP * sizeof(int));
  int* bcur0 = (int*)alloc(NBUK * sizeof(int));
  int* bcur1 = (int*)alloc(NBUK * sizeof(int));

  const float invCount = 1.f / ((float)N * (float)F);
  const uint32_t bmul = (uint32_t)(((uint64_t)NBUK << 32) / (uint64_t)N);
  const int ntiles = (N + 63) / 64;
  const int nchunkE = (E + 4095) >> 12;

  // ---- CSR build, both graphs fused ----
  kb_init<<<1, NBUK, 0, stream>>>(bcur0, bcur1, CAP);
  kb_expand<<<2 * nchunkE, 256, 0, stream>>>(ei_q, ei_k, E, nchunkE,
                                             bcur0, bcur1, pairs0, pairs1, bmul, N);
  kb_sort<<<2 * NBUK, 256, 0, stream>>>(pairs0, pairs1, bcur0, bcur1,
                                        rs0, rs1, re0, re1, csr0, csr1, bmul, CAP, N);

  // ---- layer 1 (Q: q1, K: k1) ----
  k_gemm_att<128, false><<<2 * ntiles, 256, 0, stream>>>(
      x_q, x_k, N, ntiles,
      L[0][0], L[2][0], L[0][1], L[2][1], L[0][2], L[2][2],
      nullptr, nullptr, nullptr, nullptr, nullptr, nullptr, nullptr, nullptr,
      h16_0, h16_1, hs0, hs1, hd0, hd1);
  k_aggregate<<<2 * nblk, 256, 0, stream>>>(
      rs0, rs1, re0, re1, csr0, csr1, h16_0, h16_1, hs0, hs1, hd0, hd1,
      L[0][3], L[2][3], N, nblk, y16_0, y16_1, part0, part1);
  k_ln_stats<<<2, 1024, 0, stream>>>(part0, part1, nblk, invCount, stats + 0, stats + 4);

  // ---- layer 2 (Q: q2 with q1 LN params, K: k2 with k1 LN params) ----
  k_gemm_att<64, true><<<2 * ntiles, 256, 0, stream>>>(
      y16_0, y16_1, N, ntiles,
      L[1][0], L[3][0], L[1][1], L[3][1], L[1][2], L[3][2],
      stats + 0, stats + 4, L[0][4], L[2][4], L[0][5], L[2][5], L[0][6], L[2][6],
      h16_0, h16_1, hs0, hs1, hd0, hd1);
  k_aggregate<<<2 * nblk, 256, 0, stream>>>(
      rs0, rs1, re0, re1, csr0, csr1, h16_0, h16_1, hs0, hs1, hd0, hd1,
      L[1][3], L[3][3], N, nblk, y16_0, y16_1, part0, part1);
  k_ln_stats<<<2, 1024, 0, stream>>>(part0, part1, nblk, invCount, stats + 2, stats + 6);

  // ---- fused epilogue (Q MLP head || K final LN) ----
  k_epilogue<<<ntiles + NLB, 256, 0, stream>>>(
      y16_0, y16_1, N, ntiles,
      stats + 2, stats + 6,
      L[1][4], L[1][5], L[1][6],
      mW1, mb1, mp, mW2, mb2,
      L[3][4], L[3][5], L[3][6],
      out);
}